// Round 1
// baseline (1222.641 us; speedup 1.0000x reference)
//
#include <hip/hip_runtime.h>
#include <hip/hip_bf16.h>

#define Bsz 4
#define Cm 192
#define Lseq 4096
#define Din 384
#define Dst 16
#define NCk 32
#define CLk 128   // Lseq/NCk

// ---------------- k1: gx[b,o,l] = x[b,o,l] + sum_c gw[o,c]*guide[b,c,l] ----------------
__global__ void k_guide(const float* __restrict__ x, const float* __restrict__ guide,
                        const float* __restrict__ gw, float* __restrict__ gx) {
  __shared__ float sg[192][65];
  int l0 = blockIdx.x * 64;
  int ot = blockIdx.y;           // o tile: ot*96
  int b  = blockIdx.z;
  int t  = threadIdx.x;
  for (int i = t; i < 192 * 64; i += 256) {
    int c = i >> 6, li = i & 63;
    sg[c][li] = guide[(b * 192 + c) * Lseq + l0 + li];
  }
  __syncthreads();
  int li = t & 63;
  int og = t >> 6;               // 0..3
  float acc[24];
#pragma unroll
  for (int j = 0; j < 24; j++) acc[j] = 0.f;
  for (int c = 0; c < 192; c++) {
    float gv = sg[c][li];
#pragma unroll
    for (int j = 0; j < 24; j++) {
      int o = ot * 96 + og + 4 * j;
      acc[j] = fmaf(gv, gw[o * 192 + c], acc[j]);
    }
  }
#pragma unroll
  for (int j = 0; j < 24; j++) {
    int o = ot * 96 + og + 4 * j;
    int idx = (b * 192 + o) * Lseq + l0 + li;
    gx[idx] = acc[j] + x[idx];
  }
}

// ---------------- k2: LayerNorm over C, transpose to (B,L,C) ----------------
__global__ void k_ln(const float* __restrict__ gx, const float* __restrict__ ln_g,
                     const float* __restrict__ ln_b, float* __restrict__ seq) {
  __shared__ float s[32][193];
  __shared__ float smu[32], srstd[32];
  int l0 = blockIdx.x * 32;
  int b  = blockIdx.y;
  int t  = threadIdx.x;
  for (int i = t; i < 192 * 32; i += 256) {
    int c = i >> 5, li = i & 31;
    s[li][c] = gx[(b * 192 + c) * Lseq + l0 + li];
  }
  __syncthreads();
  int li = t >> 3, j = t & 7;
  float sum = 0.f, sq = 0.f;
  for (int c = j; c < 192; c += 8) { float v = s[li][c]; sum += v; sq = fmaf(v, v, sq); }
  for (int off = 1; off < 8; off <<= 1) {
    sum += __shfl_xor(sum, off);
    sq  += __shfl_xor(sq, off);
  }
  if (j == 0) {
    float mu  = sum / 192.f;
    float var = sq / 192.f - mu * mu;
    smu[li]   = mu;
    srstd[li] = rsqrtf(var + 1e-5f);
  }
  __syncthreads();
  for (int i = t; i < 32 * 192; i += 256) {
    int li2 = i / 192, c = i % 192;
    float v = (s[li2][c] - smu[li2]) * srstd[li2] * ln_g[c] + ln_b[c];
    seq[(b * Lseq + l0 + li2) * 192 + c] = v;
  }
}

// ---------------- k3: xz[b,l,o] = sum_c seq[b,l,c]*ipw[o,c], o in [ot*256, ot*256+256) ----------------
__global__ void k_inproj(const float* __restrict__ seq, const float* __restrict__ w,
                         float* __restrict__ xz) {
  __shared__ float s[32][193];
  int l0 = blockIdx.x * 32;
  int ot = blockIdx.y;
  int b  = blockIdx.z;
  int t  = threadIdx.x;
  for (int i = t; i < 32 * 192; i += 256) {
    int li = i / 192, c = i % 192;
    s[li][c] = seq[(b * Lseq + l0 + li) * 192 + c];
  }
  __syncthreads();
  int li = t & 31, og = t >> 5;  // og 0..7
  float acc[32];
#pragma unroll
  for (int j = 0; j < 32; j++) acc[j] = 0.f;
  for (int c = 0; c < 192; c++) {
    float sv = s[li][c];
#pragma unroll
    for (int j = 0; j < 32; j++) {
      int o = ot * 256 + og + 8 * j;
      acc[j] = fmaf(sv, w[o * 192 + c], acc[j]);
    }
  }
#pragma unroll
  for (int j = 0; j < 32; j++) {
    int o = ot * 256 + og + 8 * j;
    xz[(b * Lseq + l0 + li) * 768 + o] = acc[j];
  }
}

// ---------------- k4: causal depthwise conv4 + SiLU ----------------
__global__ void k_conv(const float* __restrict__ xz, const float* __restrict__ cw,
                       const float* __restrict__ cb, float* __restrict__ u) {
  int idx = blockIdx.x * 256 + threadIdx.x;
  if (idx >= Bsz * Lseq * Din) return;
  int d = idx % Din;
  int l = (idx / Din) % Lseq;
  int b = idx / (Din * Lseq);
  float acc = cb[d];
#pragma unroll
  for (int k = 0; k < 4; k++) {
    int ls = l - 3 + k;
    if (ls >= 0) acc = fmaf(xz[(b * Lseq + ls) * 768 + d], cw[d * 4 + k], acc);
  }
  u[idx] = acc / (1.f + expf(-acc));
}

// ---------------- k5: x_proj (44) + dt_proj + softplus + split B/C ----------------
__global__ void k_xproj(const float* __restrict__ u, const float* __restrict__ xw,
                        const float* __restrict__ dtw, const float* __restrict__ dtb,
                        float* __restrict__ dt, float* __restrict__ Bc, float* __restrict__ Cc) {
  __shared__ float su[16][385];
  __shared__ float sdbc[16][44];
  int l0 = blockIdx.x * 16;
  int b  = blockIdx.y;
  int t  = threadIdx.x;
  for (int i = t; i < 16 * 384; i += 256) {
    int li = i / 384, d = i % 384;
    su[li][d] = u[(b * Lseq + l0 + li) * 384 + d];
  }
  __syncthreads();
  for (int oi = t; oi < 16 * 44; oi += 256) {
    int li = oi / 44, r = oi % 44;
    float acc = 0.f;
    for (int d = 0; d < 384; d++) acc = fmaf(su[li][d], xw[r * 384 + d], acc);
    sdbc[li][r] = acc;
  }
  __syncthreads();
  for (int oi = t; oi < 16 * 384; oi += 256) {
    int li = oi / 384, d = oi % 384;
    float acc = dtb[d];
#pragma unroll
    for (int r = 0; r < 12; r++) acc = fmaf(sdbc[li][r], dtw[d * 12 + r], acc);
    float sp = (acc > 20.f) ? acc : log1pf(expf(acc));
    dt[(b * Lseq + l0 + li) * 384 + d] = sp;
  }
  for (int oi = t; oi < 16 * 16; oi += 256) {
    int li = oi / 16, n = oi % 16;
    Bc[(b * Lseq + l0 + li) * 16 + n] = sdbc[li][12 + n];
    Cc[(b * Lseq + l0 + li) * 16 + n] = sdbc[li][28 + n];
  }
}

// ---------------- k7: scan pass1 — per-chunk (prod a, local scan from 0) ----------------
__global__ void k_scan1(const float* __restrict__ dt, const float* __restrict__ u,
                        const float* __restrict__ Bc, const float* __restrict__ Alog,
                        float* __restrict__ Aprod, float* __restrict__ Ssum) {
  int t = blockIdx.x * 256 + threadIdx.x;
  int n = t & 15;
  int g = t >> 4;
  int d = g % 384;
  int c = (g / 384) % NCk;
  int b = g / (384 * NCk);
  float A  = -expf(Alog[d * 16 + n]);
  float rA = 1.f / A;
  float h = 0.f, ap = 1.f;
  int lbase = c * CLk;
  const float* dtp = dt + (b * Lseq + lbase) * 384 + d;
  const float* up  = u  + (b * Lseq + lbase) * 384 + d;
  const float* Bp  = Bc + (b * Lseq + lbase) * 16 + n;
#pragma unroll 4
  for (int i = 0; i < CLk; i++) {
    float dtv = dtp[i * 384];
    float uv  = up[i * 384];
    float Bn  = Bp[i * 16];
    float a = expf(dtv * A);
    float s = (a - 1.f) * rA * Bn * uv;
    h  = fmaf(a, h, s);
    ap *= a;
  }
  int o = ((b * NCk + c) * 384 + d) * 16 + n;
  Aprod[o] = ap;
  Ssum[o]  = h;
}

// ---------------- k8: scan pass2 — serial chunk combine (tiny) ----------------
__global__ void k_scan2(const float* __restrict__ Aprod, const float* __restrict__ Ssum,
                        float* __restrict__ Hst) {
  int t = blockIdx.x * 256 + threadIdx.x;  // 0..24575
  int b  = t / 6144;
  int dn = t % 6144;
  float h = 0.f;
  for (int c = 0; c < NCk; c++) {
    int o = (b * NCk + c) * 6144 + dn;
    Hst[o] = h;
    h = fmaf(Aprod[o], h, Ssum[o]);
  }
}

// ---------------- k9: scan pass3 — replay with init state, y = <h,C>, gate ----------------
__global__ void k_scan3(const float* __restrict__ dt, const float* __restrict__ u,
                        const float* __restrict__ Bc, const float* __restrict__ Cc,
                        const float* __restrict__ Alog, const float* __restrict__ Hst,
                        const float* __restrict__ Dp, const float* __restrict__ xz,
                        float* __restrict__ yy) {
  int t = blockIdx.x * 256 + threadIdx.x;
  int n = t & 15;
  int g = t >> 4;
  int d = g % 384;
  int c = (g / 384) % NCk;
  int b = g / (384 * NCk);
  float A  = -expf(Alog[d * 16 + n]);
  float rA = 1.f / A;
  float h  = Hst[((b * NCk + c) * 384 + d) * 16 + n];
  float Dv = Dp[d];
  int lbase = c * CLk;
  const float* dtp = dt + (b * Lseq + lbase) * 384 + d;
  const float* up  = u  + (b * Lseq + lbase) * 384 + d;
  const float* Bp  = Bc + (b * Lseq + lbase) * 16 + n;
  const float* Cp  = Cc + (b * Lseq + lbase) * 16 + n;
  const float* zp  = xz + (b * Lseq + lbase) * 768 + 384 + d;
  float* yp = yy + (b * Lseq + lbase) * 384 + d;
#pragma unroll 4
  for (int i = 0; i < CLk; i++) {
    float dtv = dtp[i * 384];
    float uv  = up[i * 384];
    float Bn  = Bp[i * 16];
    float Cn  = Cp[i * 16];
    float a = expf(dtv * A);
    float s = (a - 1.f) * rA * Bn * uv;
    h = fmaf(a, h, s);
    float yv = h * Cn;
    yv += __shfl_xor(yv, 1);
    yv += __shfl_xor(yv, 2);
    yv += __shfl_xor(yv, 4);
    yv += __shfl_xor(yv, 8);
    if (n == 0) {
      float zv  = zp[i * 768];
      float sil = zv / (1.f + expf(-zv));
      yp[i * 384] = (yv + uv * Dv) * sil;
    }
  }
}

// ---------------- k10: out_proj + transpose to (B,192,L) ----------------
__global__ void k_outproj(const float* __restrict__ yy, const float* __restrict__ w,
                          float* __restrict__ out) {
  __shared__ float s[32][385];
  int l0 = blockIdx.x * 32;
  int b  = blockIdx.y;
  int t  = threadIdx.x;
  for (int i = t; i < 32 * 384; i += 256) {
    int li = i / 384, d = i % 384;
    s[li][d] = yy[(b * Lseq + l0 + li) * 384 + d];
  }
  __syncthreads();
  int li = t & 31, og = t >> 5;  // 0..7
  float acc[24];
#pragma unroll
  for (int j = 0; j < 24; j++) acc[j] = 0.f;
  for (int dd = 0; dd < 384; dd++) {
    float v = s[li][dd];
#pragma unroll
    for (int j = 0; j < 24; j++) {
      int o = og + 8 * j;
      acc[j] = fmaf(v, w[o * 384 + dd], acc[j]);
    }
  }
#pragma unroll
  for (int j = 0; j < 24; j++) {
    int o = og + 8 * j;
    out[(b * 192 + o) * Lseq + l0 + li] = acc[j];
  }
}

extern "C" void kernel_launch(void* const* d_in, const int* in_sizes, int n_in,
                              void* d_out, int out_size, void* d_ws, size_t ws_size,
                              hipStream_t stream) {
  const float* x    = (const float*)d_in[0];
  const float* guide= (const float*)d_in[1];
  const float* gw   = (const float*)d_in[2];
  const float* ln_g = (const float*)d_in[3];
  const float* ln_b = (const float*)d_in[4];
  const float* ipw  = (const float*)d_in[5];
  const float* cw   = (const float*)d_in[6];
  const float* cb   = (const float*)d_in[7];
  const float* xpw  = (const float*)d_in[8];
  const float* dtw  = (const float*)d_in[9];
  const float* dtb  = (const float*)d_in[10];
  const float* Alog = (const float*)d_in[11];
  const float* Dp   = (const float*)d_in[12];
  const float* opw  = (const float*)d_in[13];
  float* out = (float*)d_out;
  float* ws  = (float*)d_ws;

  float* gx  = ws + 0;          // 3145728
  float* seq = ws + 3145728;    // 3145728
  float* xz  = ws + 6291456;    // 12582912
  float* u   = ws + 18874368;   // 6291456
  float* dt  = ws + 25165824;   // 6291456
  float* Bc_ = ws + 31457280;   // 262144
  float* Cc_ = ws + 31719424;   // 262144
  float* Ap  = ws + 31981568;   // 786432
  float* Ss  = ws + 32768000;   // 786432
  float* Hs  = ws + 33554432;   // 786432
  float* yy  = ws + 0;          // reuse gx+seq region (dead by then), 6291456

  k_guide  <<<dim3(64, 2, 4),  256, 0, stream>>>(x, guide, gw, gx);
  k_ln     <<<dim3(128, 4),    256, 0, stream>>>(gx, ln_g, ln_b, seq);
  k_inproj <<<dim3(128, 3, 4), 256, 0, stream>>>(seq, ipw, xz);
  k_conv   <<<24576,           256, 0, stream>>>(xz, cw, cb, u);
  k_xproj  <<<dim3(256, 4),    256, 0, stream>>>(u, xpw, dtw, dtb, dt, Bc_, Cc_);
  k_scan1  <<<3072,            256, 0, stream>>>(dt, u, Bc_, Alog, Ap, Ss);
  k_scan2  <<<96,              256, 0, stream>>>(Ap, Ss, Hs);
  k_scan3  <<<3072,            256, 0, stream>>>(dt, u, Bc_, Cc_, Alog, Hs, Dp, xz, yy);
  k_outproj<<<dim3(128, 4),    256, 0, stream>>>(yy, opw, out);
}

// Round 2
// 583.412 us; speedup vs baseline: 2.0957x; 2.0957x over previous
//
#include <hip/hip_runtime.h>
#include <hip/hip_bf16.h>

#define Bsz 4
#define Cm 192
#define Lseq 4096
#define Din 384
#define Dst 16
#define NCk 32
#define CLk 128   // Lseq/NCk

// ======================= Tiled fp32 GEMM building blocks =======================
// Block tile: 128 M x 64 N, K-chunk 64. 256 threads, per-thread 8M x 4N.
// LDS: sA[64][132] (k-major, padded), sB[64][68].
#define SA_P 132
#define SB_P 68

// Stage A chunk when A is row-major (row, K): sA[cc][m] = A[(rowbase+m)*Kp + c0+cc]
__device__ __forceinline__ void stageA_rowmajor(const float* __restrict__ A, int rowbase,
                                                int Kp, int c0, float* sA, int t) {
  int m = t >> 1;            // 0..127
  int cg = (t & 1) * 32;     // 0 or 32
  const float* src = A + (long)(rowbase + m) * Kp + c0 + cg;
#pragma unroll
  for (int j = 0; j < 8; j++) {
    float4 v = *(const float4*)(src + j * 4);
    int cc = cg + j * 4;
    sA[(cc + 0) * SA_P + m] = v.x;
    sA[(cc + 1) * SA_P + m] = v.y;
    sA[(cc + 2) * SA_P + m] = v.z;
    sA[(cc + 3) * SA_P + m] = v.w;
  }
}

// Stage A chunk when A is col-major (K, M) i.e. M contiguous: sA[cc][m] = A[(c0+cc)*Mp + l0+m]
__device__ __forceinline__ void stageA_colmajor(const float* __restrict__ A, long cbase,
                                                int Mp, int l0, float* sA, int t) {
  int cc = t >> 2;           // 0..63
  int mg = (t & 3) * 32;
  const float* src = A + (cbase + cc) * Mp + l0 + mg;
  float* dst = sA + cc * SA_P + mg;
#pragma unroll
  for (int j = 0; j < 8; j++) {
    *(float4*)(dst + j * 4) = *(const float4*)(src + j * 4);
  }
}

// Stage B chunk, B row-major (N, K): sB[cc][n] = B[(nbase+n)*Kp + c0+cc]; rows >= Nmax -> 0
__device__ __forceinline__ void stageB(const float* __restrict__ B, int nbase, int Kp,
                                       int c0, int Nmax, float* sB, int t) {
  int n = t >> 2;            // 0..63
  int cg = (t & 3) * 16;
  bool ok = (nbase + n) < Nmax;
  const float* src = B + (long)(nbase + n) * Kp + c0 + cg;
#pragma unroll
  for (int j = 0; j < 4; j++) {
    float4 v = ok ? *(const float4*)(src + j * 4) : make_float4(0.f, 0.f, 0.f, 0.f);
    int cc = cg + j * 4;
    sB[(cc + 0) * SB_P + n] = v.x;
    sB[(cc + 1) * SB_P + n] = v.y;
    sB[(cc + 2) * SB_P + n] = v.z;
    sB[(cc + 3) * SB_P + n] = v.w;
  }
}

__device__ __forceinline__ void gemm_inner(const float* sA, const float* sB, int m0, int n0,
                                           float acc[8][4]) {
#pragma unroll
  for (int cc = 0; cc < 64; cc++) {
    float4 bv = *(const float4*)(sB + cc * SB_P + n0);
    float4 a0 = *(const float4*)(sA + cc * SA_P + m0);
    float4 a1 = *(const float4*)(sA + cc * SA_P + m0 + 4);
    float am[8] = {a0.x, a0.y, a0.z, a0.w, a1.x, a1.y, a1.z, a1.w};
    float bn[4] = {bv.x, bv.y, bv.z, bv.w};
#pragma unroll
    for (int mi = 0; mi < 8; mi++)
#pragma unroll
      for (int ni = 0; ni < 4; ni++)
        acc[mi][ni] = fmaf(am[mi], bn[ni], acc[mi][ni]);
  }
}

// ---------------- guide GEMM: gx[b,o,l] = x[b,o,l] + sum_c gw[o,c]*guide[b,c,l] ----------------
__global__ void k_guide(const float* __restrict__ x, const float* __restrict__ guide,
                        const float* __restrict__ gw, float* __restrict__ gx) {
  __shared__ float sA[64 * SA_P];
  __shared__ float sB[64 * SB_P];
  int t = threadIdx.x;
  int l0 = blockIdx.x * 128;
  int nbase = blockIdx.y * 64;
  int b = blockIdx.z;
  int tx = t & 15, ty = t >> 4;
  int n0 = tx * 4, m0 = ty * 8;
  float acc[8][4];
#pragma unroll
  for (int i = 0; i < 8; i++)
#pragma unroll
    for (int j = 0; j < 4; j++) acc[i][j] = 0.f;
  for (int c0 = 0; c0 < 192; c0 += 64) {
    if (c0) __syncthreads();
    stageA_colmajor(guide, (long)b * 192 + c0, Lseq, l0, sA, t);
    stageB(gw, nbase, 192, c0, 192, sB, t);
    __syncthreads();
    gemm_inner(sA, sB, m0, n0, acc);
  }
#pragma unroll
  for (int ni = 0; ni < 4; ni++) {
    int o = nbase + n0 + ni;
    long base = ((long)b * 192 + o) * Lseq + l0 + m0;
    float4 x0 = *(const float4*)(x + base);
    float4 x1 = *(const float4*)(x + base + 4);
    float4 r0 = make_float4(acc[0][ni] + x0.x, acc[1][ni] + x0.y, acc[2][ni] + x0.z, acc[3][ni] + x0.w);
    float4 r1 = make_float4(acc[4][ni] + x1.x, acc[5][ni] + x1.y, acc[6][ni] + x1.z, acc[7][ni] + x1.w);
    *(float4*)(gx + base) = r0;
    *(float4*)(gx + base + 4) = r1;
  }
}

// ---------------- k2: LayerNorm over C, transpose to (B,L,C) ----------------
__global__ void k_ln(const float* __restrict__ gx, const float* __restrict__ ln_g,
                     const float* __restrict__ ln_b, float* __restrict__ seq) {
  __shared__ float s[32][193];
  __shared__ float smu[32], srstd[32];
  int l0 = blockIdx.x * 32;
  int b  = blockIdx.y;
  int t  = threadIdx.x;
  for (int i = t; i < 192 * 32; i += 256) {
    int c = i >> 5, li = i & 31;
    s[li][c] = gx[(b * 192 + c) * Lseq + l0 + li];
  }
  __syncthreads();
  int li = t >> 3, j = t & 7;
  float sum = 0.f, sq = 0.f;
  for (int c = j; c < 192; c += 8) { float v = s[li][c]; sum += v; sq = fmaf(v, v, sq); }
  for (int off = 1; off < 8; off <<= 1) {
    sum += __shfl_xor(sum, off);
    sq  += __shfl_xor(sq, off);
  }
  if (j == 0) {
    float mu  = sum / 192.f;
    float var = sq / 192.f - mu * mu;
    smu[li]   = mu;
    srstd[li] = rsqrtf(var + 1e-5f);
  }
  __syncthreads();
  for (int i = t; i < 32 * 192; i += 256) {
    int li2 = i / 192, c = i % 192;
    float v = (s[li2][c] - smu[li2]) * srstd[li2] * ln_g[c] + ln_b[c];
    seq[(b * Lseq + l0 + li2) * 192 + c] = v;
  }
}

// ---------------- in_proj GEMM: xz[row,o] = sum_c seq[row,c]*ipw[o,c] ----------------
__global__ void k_inproj(const float* __restrict__ seq, const float* __restrict__ w,
                         float* __restrict__ xz) {
  __shared__ float sA[64 * SA_P];
  __shared__ float sB[64 * SB_P];
  int t = threadIdx.x;
  int rowbase = blockIdx.x * 128;
  int nbase = blockIdx.y * 64;
  int tx = t & 15, ty = t >> 4;
  int n0 = tx * 4, m0 = ty * 8;
  float acc[8][4];
#pragma unroll
  for (int i = 0; i < 8; i++)
#pragma unroll
    for (int j = 0; j < 4; j++) acc[i][j] = 0.f;
  for (int c0 = 0; c0 < 192; c0 += 64) {
    if (c0) __syncthreads();
    stageA_rowmajor(seq, rowbase, 192, c0, sA, t);
    stageB(w, nbase, 192, c0, 768, sB, t);
    __syncthreads();
    gemm_inner(sA, sB, m0, n0, acc);
  }
#pragma unroll
  for (int mi = 0; mi < 8; mi++) {
    long row = rowbase + m0 + mi;
    *(float4*)(xz + row * 768 + nbase + n0) =
        make_float4(acc[mi][0], acc[mi][1], acc[mi][2], acc[mi][3]);
  }
}

// ---------------- causal depthwise conv4 + SiLU ----------------
__global__ void k_conv(const float* __restrict__ xz, const float* __restrict__ cw,
                       const float* __restrict__ cb, float* __restrict__ u) {
  int idx = blockIdx.x * 256 + threadIdx.x;
  if (idx >= Bsz * Lseq * Din) return;
  int d = idx % Din;
  int l = (idx / Din) % Lseq;
  int b = idx / (Din * Lseq);
  float acc = cb[d];
#pragma unroll
  for (int k = 0; k < 4; k++) {
    int ls = l - 3 + k;
    if (ls >= 0) acc = fmaf(xz[(b * Lseq + ls) * 768 + d], cw[d * 4 + k], acc);
  }
  u[idx] = acc / (1.f + expf(-acc));
}

// ---------------- x_proj GEMM: dbc[row, r] = sum_d u[row,d]*xpw[r,d], r < 44, pitch 48 ----------------
__global__ void k_xproj(const float* __restrict__ u, const float* __restrict__ xw,
                        float* __restrict__ dbc) {
  __shared__ float sA[64 * SA_P];
  __shared__ float sB[64 * SB_P];
  int t = threadIdx.x;
  int rowbase = blockIdx.x * 128;
  int tx = t & 15, ty = t >> 4;
  int n0 = tx * 4, m0 = ty * 8;
  float acc[8][4];
#pragma unroll
  for (int i = 0; i < 8; i++)
#pragma unroll
    for (int j = 0; j < 4; j++) acc[i][j] = 0.f;
  for (int c0 = 0; c0 < 384; c0 += 64) {
    if (c0) __syncthreads();
    stageA_rowmajor(u, rowbase, 384, c0, sA, t);
    stageB(xw, 0, 384, c0, 44, sB, t);
    __syncthreads();
    gemm_inner(sA, sB, m0, n0, acc);
  }
  if (tx < 11) {
#pragma unroll
    for (int mi = 0; mi < 8; mi++) {
      long row = rowbase + m0 + mi;
      *(float4*)(dbc + row * 48 + n0) =
          make_float4(acc[mi][0], acc[mi][1], acc[mi][2], acc[mi][3]);
    }
  }
}

// ---------------- dt_proj + softplus + B/C split ----------------
__global__ void k_dtsplit(const float* __restrict__ dbc, const float* __restrict__ dtw,
                          const float* __restrict__ dtb, float* __restrict__ dt,
                          float* __restrict__ Bc, float* __restrict__ Cc) {
  int idx = blockIdx.x * 256 + threadIdx.x;
  int row = idx / 384;
  int d = idx % 384;
  const float* p = dbc + (long)row * 48;
  float acc = dtb[d];
#pragma unroll
  for (int r = 0; r < 12; r++) acc = fmaf(p[r], dtw[d * 12 + r], acc);
  float sp = (acc > 20.f) ? acc : log1pf(expf(acc));
  dt[(long)row * 384 + d] = sp;
  if (d < 16) Bc[row * 16 + d] = p[12 + d];
  else if (d < 32) Cc[row * 16 + (d - 16)] = p[28 + (d - 16)];
}

// ---------------- scan pass1 — per-chunk (prod a, local scan from 0) ----------------
__global__ void k_scan1(const float* __restrict__ dt, const float* __restrict__ u,
                        const float* __restrict__ Bc, const float* __restrict__ Alog,
                        float* __restrict__ Aprod, float* __restrict__ Ssum) {
  int t = blockIdx.x * 256 + threadIdx.x;
  int n = t & 15;
  int g = t >> 4;
  int d = g % 384;
  int c = (g / 384) % NCk;
  int b = g / (384 * NCk);
  float A  = -expf(Alog[d * 16 + n]);
  float rA = 1.f / A;
  float h = 0.f, ap = 1.f;
  int lbase = c * CLk;
  const float* dtp = dt + (b * Lseq + lbase) * 384 + d;
  const float* up  = u  + (b * Lseq + lbase) * 384 + d;
  const float* Bp  = Bc + (b * Lseq + lbase) * 16 + n;
#pragma unroll 4
  for (int i = 0; i < CLk; i++) {
    float dtv = dtp[i * 384];
    float uv  = up[i * 384];
    float Bn  = Bp[i * 16];
    float a = expf(dtv * A);
    float s = (a - 1.f) * rA * Bn * uv;
    h  = fmaf(a, h, s);
    ap *= a;
  }
  int o = ((b * NCk + c) * 384 + d) * 16 + n;
  Aprod[o] = ap;
  Ssum[o]  = h;
}

// ---------------- scan pass2 — serial chunk combine (tiny) ----------------
__global__ void k_scan2(const float* __restrict__ Aprod, const float* __restrict__ Ssum,
                        float* __restrict__ Hst) {
  int t = blockIdx.x * 256 + threadIdx.x;  // 0..24575
  int b  = t / 6144;
  int dn = t % 6144;
  float h = 0.f;
  for (int c = 0; c < NCk; c++) {
    int o = (b * NCk + c) * 6144 + dn;
    Hst[o] = h;
    h = fmaf(Aprod[o], h, Ssum[o]);
  }
}

// ---------------- scan pass3 — replay with init state, y = <h,C>, gate ----------------
__global__ void k_scan3(const float* __restrict__ dt, const float* __restrict__ u,
                        const float* __restrict__ Bc, const float* __restrict__ Cc,
                        const float* __restrict__ Alog, const float* __restrict__ Hst,
                        const float* __restrict__ Dp, const float* __restrict__ xz,
                        float* __restrict__ yy) {
  int t = blockIdx.x * 256 + threadIdx.x;
  int n = t & 15;
  int g = t >> 4;
  int d = g % 384;
  int c = (g / 384) % NCk;
  int b = g / (384 * NCk);
  float A  = -expf(Alog[d * 16 + n]);
  float rA = 1.f / A;
  float h  = Hst[((b * NCk + c) * 384 + d) * 16 + n];
  float Dv = Dp[d];
  int lbase = c * CLk;
  const float* dtp = dt + (b * Lseq + lbase) * 384 + d;
  const float* up  = u  + (b * Lseq + lbase) * 384 + d;
  const float* Bp  = Bc + (b * Lseq + lbase) * 16 + n;
  const float* Cp  = Cc + (b * Lseq + lbase) * 16 + n;
  const float* zp  = xz + (b * Lseq + lbase) * 768 + 384 + d;
  float* yp = yy + (b * Lseq + lbase) * 384 + d;
#pragma unroll 4
  for (int i = 0; i < CLk; i++) {
    float dtv = dtp[i * 384];
    float uv  = up[i * 384];
    float Bn  = Bp[i * 16];
    float Cn  = Cp[i * 16];
    float a = expf(dtv * A);
    float s = (a - 1.f) * rA * Bn * uv;
    h = fmaf(a, h, s);
    float yv = h * Cn;
    yv += __shfl_xor(yv, 1);
    yv += __shfl_xor(yv, 2);
    yv += __shfl_xor(yv, 4);
    yv += __shfl_xor(yv, 8);
    if (n == 0) {
      float zv  = zp[i * 768];
      float sil = zv / (1.f + expf(-zv));
      yp[i * 384] = (yv + uv * Dv) * sil;
    }
  }
}

// ---------------- out_proj GEMM: out[b,o,l] = sum_d yy[row,d]*opw[o,d] ----------------
__global__ void k_outproj(const float* __restrict__ yy, const float* __restrict__ w,
                          float* __restrict__ out) {
  __shared__ float sA[64 * SA_P];
  __shared__ float sB[64 * SB_P];
  int t = threadIdx.x;
  int rowbase = blockIdx.x * 128;
  int nbase = blockIdx.y * 64;
  int tx = t & 15, ty = t >> 4;
  int n0 = tx * 4, m0 = ty * 8;
  float acc[8][4];
#pragma unroll
  for (int i = 0; i < 8; i++)
#pragma unroll
    for (int j = 0; j < 4; j++) acc[i][j] = 0.f;
  for (int c0 = 0; c0 < 384; c0 += 64) {
    if (c0) __syncthreads();
    stageA_rowmajor(yy, rowbase, 384, c0, sA, t);
    stageB(w, nbase, 384, c0, 192, sB, t);
    __syncthreads();
    gemm_inner(sA, sB, m0, n0, acc);
  }
  int b = rowbase / Lseq;
  int l0 = rowbase - b * Lseq + m0;
#pragma unroll
  for (int ni = 0; ni < 4; ni++) {
    int o = nbase + n0 + ni;
    long base = ((long)b * 192 + o) * Lseq + l0;
    *(float4*)(out + base) = make_float4(acc[0][ni], acc[1][ni], acc[2][ni], acc[3][ni]);
    *(float4*)(out + base + 4) = make_float4(acc[4][ni], acc[5][ni], acc[6][ni], acc[7][ni]);
  }
}

extern "C" void kernel_launch(void* const* d_in, const int* in_sizes, int n_in,
                              void* d_out, int out_size, void* d_ws, size_t ws_size,
                              hipStream_t stream) {
  const float* x    = (const float*)d_in[0];
  const float* guide= (const float*)d_in[1];
  const float* gw   = (const float*)d_in[2];
  const float* ln_g = (const float*)d_in[3];
  const float* ln_b = (const float*)d_in[4];
  const float* ipw  = (const float*)d_in[5];
  const float* cw   = (const float*)d_in[6];
  const float* cb   = (const float*)d_in[7];
  const float* xpw  = (const float*)d_in[8];
  const float* dtw  = (const float*)d_in[9];
  const float* dtb  = (const float*)d_in[10];
  const float* Alog = (const float*)d_in[11];
  const float* Dp   = (const float*)d_in[12];
  const float* opw  = (const float*)d_in[13];
  float* out = (float*)d_out;
  float* ws  = (float*)d_ws;

  float* gx  = ws + 0;          // 3145728
  float* seq = ws + 3145728;    // 3145728
  float* xz  = ws + 6291456;    // 12582912
  float* u   = ws + 18874368;   // 6291456
  float* dt  = ws + 25165824;   // 6291456
  float* Bc_ = ws + 31457280;   // 262144
  float* Cc_ = ws + 31719424;   // 262144
  float* Ap  = ws + 31981568;   // 786432
  float* Ss  = ws + 32768000;   // 786432
  float* Hs  = ws + 33554432;   // 786432
  float* dbc = ws + 0;          // reuse gx region (dead after k_ln feeds inproj... gx read by k_ln only; seq dead after inproj) — dbc written by k_xproj (after), read by k_dtsplit
  float* yy  = ws + 0;          // written by scan3 after dbc consumed; read by outproj

  k_guide  <<<dim3(32, 3, 4),  256, 0, stream>>>(x, guide, gw, gx);
  k_ln     <<<dim3(128, 4),    256, 0, stream>>>(gx, ln_g, ln_b, seq);
  k_inproj <<<dim3(128, 12),   256, 0, stream>>>(seq, ipw, xz);
  k_conv   <<<24576,           256, 0, stream>>>(xz, cw, cb, u);
  k_xproj  <<<dim3(128, 1),    256, 0, stream>>>(u, xpw, dbc);
  k_dtsplit<<<24576,           256, 0, stream>>>(dbc, dtw, dtb, dt, Bc_, Cc_);
  k_scan1  <<<3072,            256, 0, stream>>>(dt, u, Bc_, Alog, Ap, Ss);
  k_scan2  <<<96,              256, 0, stream>>>(Ap, Ss, Hs);
  k_scan3  <<<3072,            256, 0, stream>>>(dt, u, Bc_, Cc_, Alog, Hs, Dp, xz, yy);
  k_outproj<<<dim3(128, 3),    256, 0, stream>>>(yy, opw, out);
}

// Round 3
// 552.103 us; speedup vs baseline: 2.2145x; 1.0567x over previous
//
#include <hip/hip_runtime.h>
#include <hip/hip_bf16.h>

#define Bsz 4
#define Cm 192
#define Lseq 4096
#define Din 384
#define Dst 16
#define NCk 32
#define CLk 128   // Lseq/NCk

// ======================= Tiled fp32 GEMM building blocks =======================
// Block tile: 128 M x 64 N, K-chunk 64. 256 threads, per-thread 8M x 4N.
// LDS: sA[64][132] (k-major, padded), sB[64][68].
#define SA_P 132
#define SB_P 68

// Stage A chunk when A is row-major (row, K): sA[cc][m] = A[(rowbase+m)*Kp + c0+cc]
__device__ __forceinline__ void stageA_rowmajor(const float* __restrict__ A, int rowbase,
                                                int Kp, int c0, float* sA, int t) {
  int m = t >> 1;            // 0..127
  int cg = (t & 1) * 32;     // 0 or 32
  const float* src = A + (long)(rowbase + m) * Kp + c0 + cg;
#pragma unroll
  for (int j = 0; j < 8; j++) {
    float4 v = *(const float4*)(src + j * 4);
    int cc = cg + j * 4;
    sA[(cc + 0) * SA_P + m] = v.x;
    sA[(cc + 1) * SA_P + m] = v.y;
    sA[(cc + 2) * SA_P + m] = v.z;
    sA[(cc + 3) * SA_P + m] = v.w;
  }
}

// Stage A chunk when A is col-major (K, M) i.e. M contiguous: sA[cc][m] = A[(c0+cc)*Mp + l0+m]
__device__ __forceinline__ void stageA_colmajor(const float* __restrict__ A, long cbase,
                                                int Mp, int l0, float* sA, int t) {
  int cc = t >> 2;           // 0..63
  int mg = (t & 3) * 32;
  const float* src = A + (cbase + cc) * Mp + l0 + mg;
  float* dst = sA + cc * SA_P + mg;
#pragma unroll
  for (int j = 0; j < 8; j++) {
    *(float4*)(dst + j * 4) = *(const float4*)(src + j * 4);
  }
}

// Stage B chunk, B row-major (N, K): sB[cc][n] = B[(nbase+n)*Kp + c0+cc]; rows >= Nmax -> 0
__device__ __forceinline__ void stageB(const float* __restrict__ B, int nbase, int Kp,
                                       int c0, int Nmax, float* sB, int t) {
  int n = t >> 2;            // 0..63
  int cg = (t & 3) * 16;
  bool ok = (nbase + n) < Nmax;
  const float* src = B + (long)(nbase + n) * Kp + c0 + cg;
#pragma unroll
  for (int j = 0; j < 4; j++) {
    float4 v = ok ? *(const float4*)(src + j * 4) : make_float4(0.f, 0.f, 0.f, 0.f);
    int cc = cg + j * 4;
    sB[(cc + 0) * SB_P + n] = v.x;
    sB[(cc + 1) * SB_P + n] = v.y;
    sB[(cc + 2) * SB_P + n] = v.z;
    sB[(cc + 3) * SB_P + n] = v.w;
  }
}

__device__ __forceinline__ void gemm_inner(const float* sA, const float* sB, int m0, int n0,
                                           float acc[8][4]) {
#pragma unroll
  for (int cc = 0; cc < 64; cc++) {
    float4 bv = *(const float4*)(sB + cc * SB_P + n0);
    float4 a0 = *(const float4*)(sA + cc * SA_P + m0);
    float4 a1 = *(const float4*)(sA + cc * SA_P + m0 + 4);
    float am[8] = {a0.x, a0.y, a0.z, a0.w, a1.x, a1.y, a1.z, a1.w};
    float bn[4] = {bv.x, bv.y, bv.z, bv.w};
#pragma unroll
    for (int mi = 0; mi < 8; mi++)
#pragma unroll
      for (int ni = 0; ni < 4; ni++)
        acc[mi][ni] = fmaf(am[mi], bn[ni], acc[mi][ni]);
  }
}

// ---------------- guide GEMM: gx[b,o,l] = x[b,o,l] + sum_c gw[o,c]*guide[b,c,l] ----------------
__global__ void k_guide(const float* __restrict__ x, const float* __restrict__ guide,
                        const float* __restrict__ gw, float* __restrict__ gx) {
  __shared__ float sA[64 * SA_P];
  __shared__ float sB[64 * SB_P];
  int t = threadIdx.x;
  int l0 = blockIdx.x * 128;
  int nbase = blockIdx.y * 64;
  int b = blockIdx.z;
  int tx = t & 15, ty = t >> 4;
  int n0 = tx * 4, m0 = ty * 8;
  float acc[8][4];
#pragma unroll
  for (int i = 0; i < 8; i++)
#pragma unroll
    for (int j = 0; j < 4; j++) acc[i][j] = 0.f;
  for (int c0 = 0; c0 < 192; c0 += 64) {
    if (c0) __syncthreads();
    stageA_colmajor(guide, (long)b * 192 + c0, Lseq, l0, sA, t);
    stageB(gw, nbase, 192, c0, 192, sB, t);
    __syncthreads();
    gemm_inner(sA, sB, m0, n0, acc);
  }
#pragma unroll
  for (int ni = 0; ni < 4; ni++) {
    int o = nbase + n0 + ni;
    long base = ((long)b * 192 + o) * Lseq + l0 + m0;
    float4 x0 = *(const float4*)(x + base);
    float4 x1 = *(const float4*)(x + base + 4);
    float4 r0 = make_float4(acc[0][ni] + x0.x, acc[1][ni] + x0.y, acc[2][ni] + x0.z, acc[3][ni] + x0.w);
    float4 r1 = make_float4(acc[4][ni] + x1.x, acc[5][ni] + x1.y, acc[6][ni] + x1.z, acc[7][ni] + x1.w);
    *(float4*)(gx + base) = r0;
    *(float4*)(gx + base + 4) = r1;
  }
}

// ---------------- k2: LayerNorm over C, transpose to (B,L,C) ----------------
__global__ void k_ln(const float* __restrict__ gx, const float* __restrict__ ln_g,
                     const float* __restrict__ ln_b, float* __restrict__ seq) {
  __shared__ float s[32][193];
  __shared__ float smu[32], srstd[32];
  int l0 = blockIdx.x * 32;
  int b  = blockIdx.y;
  int t  = threadIdx.x;
  for (int i = t; i < 192 * 32; i += 256) {
    int c = i >> 5, li = i & 31;
    s[li][c] = gx[(b * 192 + c) * Lseq + l0 + li];
  }
  __syncthreads();
  int li = t >> 3, j = t & 7;
  float sum = 0.f, sq = 0.f;
  for (int c = j; c < 192; c += 8) { float v = s[li][c]; sum += v; sq = fmaf(v, v, sq); }
  for (int off = 1; off < 8; off <<= 1) {
    sum += __shfl_xor(sum, off);
    sq  += __shfl_xor(sq, off);
  }
  if (j == 0) {
    float mu  = sum / 192.f;
    float var = sq / 192.f - mu * mu;
    smu[li]   = mu;
    srstd[li] = rsqrtf(var + 1e-5f);
  }
  __syncthreads();
  for (int i = t; i < 32 * 192; i += 256) {
    int li2 = i / 192, c = i % 192;
    float v = (s[li2][c] - smu[li2]) * srstd[li2] * ln_g[c] + ln_b[c];
    seq[(b * Lseq + l0 + li2) * 192 + c] = v;
  }
}

// ---------------- in_proj GEMM: xz[row,o] = sum_c seq[row,c]*ipw[o,c] ----------------
__global__ void k_inproj(const float* __restrict__ seq, const float* __restrict__ w,
                         float* __restrict__ xz) {
  __shared__ float sA[64 * SA_P];
  __shared__ float sB[64 * SB_P];
  int t = threadIdx.x;
  int rowbase = blockIdx.x * 128;
  int nbase = blockIdx.y * 64;
  int tx = t & 15, ty = t >> 4;
  int n0 = tx * 4, m0 = ty * 8;
  float acc[8][4];
#pragma unroll
  for (int i = 0; i < 8; i++)
#pragma unroll
    for (int j = 0; j < 4; j++) acc[i][j] = 0.f;
  for (int c0 = 0; c0 < 192; c0 += 64) {
    if (c0) __syncthreads();
    stageA_rowmajor(seq, rowbase, 192, c0, sA, t);
    stageB(w, nbase, 192, c0, 768, sB, t);
    __syncthreads();
    gemm_inner(sA, sB, m0, n0, acc);
  }
#pragma unroll
  for (int mi = 0; mi < 8; mi++) {
    long row = rowbase + m0 + mi;
    *(float4*)(xz + row * 768 + nbase + n0) =
        make_float4(acc[mi][0], acc[mi][1], acc[mi][2], acc[mi][3]);
  }
}

// ---------------- causal depthwise conv4 + SiLU ----------------
__global__ void k_conv(const float* __restrict__ xz, const float* __restrict__ cw,
                       const float* __restrict__ cb, float* __restrict__ u) {
  int idx = blockIdx.x * 256 + threadIdx.x;
  if (idx >= Bsz * Lseq * Din) return;
  int d = idx % Din;
  int l = (idx / Din) % Lseq;
  int b = idx / (Din * Lseq);
  float acc = cb[d];
#pragma unroll
  for (int k = 0; k < 4; k++) {
    int ls = l - 3 + k;
    if (ls >= 0) acc = fmaf(xz[(b * Lseq + ls) * 768 + d], cw[d * 4 + k], acc);
  }
  u[idx] = acc / (1.f + __expf(-acc));
}

// ---------------- x_proj GEMM: dbc[row, r] = sum_d u[row,d]*xpw[r,d], r < 44, pitch 48 ----------------
__global__ void k_xproj(const float* __restrict__ u, const float* __restrict__ xw,
                        float* __restrict__ dbc) {
  __shared__ float sA[64 * SA_P];
  __shared__ float sB[64 * SB_P];
  int t = threadIdx.x;
  int rowbase = blockIdx.x * 128;
  int tx = t & 15, ty = t >> 4;
  int n0 = tx * 4, m0 = ty * 8;
  float acc[8][4];
#pragma unroll
  for (int i = 0; i < 8; i++)
#pragma unroll
    for (int j = 0; j < 4; j++) acc[i][j] = 0.f;
  for (int c0 = 0; c0 < 384; c0 += 64) {
    if (c0) __syncthreads();
    stageA_rowmajor(u, rowbase, 384, c0, sA, t);
    stageB(xw, 0, 384, c0, 44, sB, t);
    __syncthreads();
    gemm_inner(sA, sB, m0, n0, acc);
  }
  if (tx < 11) {
#pragma unroll
    for (int mi = 0; mi < 8; mi++) {
      long row = rowbase + m0 + mi;
      *(float4*)(dbc + row * 48 + n0) =
          make_float4(acc[mi][0], acc[mi][1], acc[mi][2], acc[mi][3]);
    }
  }
}

// ---------------- dt_proj + softplus + B/C split ----------------
__global__ void k_dtsplit(const float* __restrict__ dbc, const float* __restrict__ dtw,
                          const float* __restrict__ dtb, float* __restrict__ dt,
                          float* __restrict__ Bc, float* __restrict__ Cc) {
  int idx = blockIdx.x * 256 + threadIdx.x;
  int row = idx / 384;
  int d = idx % 384;
  const float* p = dbc + (long)row * 48;
  float acc = dtb[d];
#pragma unroll
  for (int r = 0; r < 12; r++) acc = fmaf(p[r], dtw[d * 12 + r], acc);
  float sp = (acc > 20.f) ? acc : __logf(1.f + __expf(acc));
  dt[(long)row * 384 + d] = sp;
  if (d < 16) Bc[row * 16 + d] = p[12 + d];
  else if (d < 32) Cc[row * 16 + (d - 16)] = p[28 + (d - 16)];
}

// ---------------- scan pass1 — per-chunk (prod a, local scan from 0) ----------------
__global__ void k_scan1(const float* __restrict__ dt, const float* __restrict__ u,
                        const float* __restrict__ Bc, const float* __restrict__ Alog,
                        float* __restrict__ Aprod, float* __restrict__ Ssum) {
  int t = blockIdx.x * 256 + threadIdx.x;
  int n = t & 15;
  int g = t >> 4;
  int d = g % 384;
  int c = (g / 384) % NCk;
  int b = g / (384 * NCk);
  float A  = -__expf(Alog[d * 16 + n]);
  float rA = 1.f / A;
  float h = 0.f, sdt = 0.f;
  int lbase = c * CLk;
  const float* dtp = dt + (b * Lseq + lbase) * 384 + d;
  const float* up  = u  + (b * Lseq + lbase) * 384 + d;
  const float* Bp  = Bc + (b * Lseq + lbase) * 16 + n;
#pragma unroll 4
  for (int i = 0; i < CLk; i++) {
    float dtv = dtp[i * 384];
    float uv  = up[i * 384];
    float Bn  = Bp[i * 16];
    float a = __expf(dtv * A);
    float s = (a - 1.f) * rA * Bn * uv;
    h  = fmaf(a, h, s);
    sdt += dtv;
  }
  int o = ((b * NCk + c) * 384 + d) * 16 + n;
  Aprod[o] = __expf(sdt * A);
  Ssum[o]  = h;
}

// ---------------- scan pass2 — serial chunk combine (tiny) ----------------
__global__ void k_scan2(const float* __restrict__ Aprod, const float* __restrict__ Ssum,
                        float* __restrict__ Hst) {
  int t = blockIdx.x * 256 + threadIdx.x;  // 0..24575
  int b  = t / 6144;
  int dn = t % 6144;
  float h = 0.f;
  for (int c = 0; c < NCk; c++) {
    int o = (b * NCk + c) * 6144 + dn;
    Hst[o] = h;
    h = fmaf(Aprod[o], h, Ssum[o]);
  }
}

// ---------------- scan pass3 — replay with init state, y = <h,C>, gate ----------------
__global__ void k_scan3(const float* __restrict__ dt, const float* __restrict__ u,
                        const float* __restrict__ Bc, const float* __restrict__ Cc,
                        const float* __restrict__ Alog, const float* __restrict__ Hst,
                        const float* __restrict__ Dp, const float* __restrict__ xz,
                        float* __restrict__ yy) {
  int t = blockIdx.x * 256 + threadIdx.x;
  int n = t & 15;
  int g = t >> 4;
  int d = g % 384;
  int c = (g / 384) % NCk;
  int b = g / (384 * NCk);
  float A  = -__expf(Alog[d * 16 + n]);
  float rA = 1.f / A;
  float h  = Hst[((b * NCk + c) * 384 + d) * 16 + n];
  float Dv = Dp[d];
  int lbase = c * CLk;
  const float* dtp = dt + (b * Lseq + lbase) * 384 + d;
  const float* up  = u  + (b * Lseq + lbase) * 384 + d;
  const float* Bp  = Bc + (b * Lseq + lbase) * 16 + n;
  const float* Cp  = Cc + (b * Lseq + lbase) * 16 + n;
  const float* zp  = xz + (b * Lseq + lbase) * 768 + 384 + d;
  float* yp = yy + (b * Lseq + lbase) * 384 + d;
#pragma unroll 4
  for (int i = 0; i < CLk; i++) {
    float dtv = dtp[i * 384];
    float uv  = up[i * 384];
    float Bn  = Bp[i * 16];
    float Cn  = Cp[i * 16];
    float a = __expf(dtv * A);
    float s = (a - 1.f) * rA * Bn * uv;
    h = fmaf(a, h, s);
    float yv = h * Cn;
    yv += __shfl_xor(yv, 1);
    yv += __shfl_xor(yv, 2);
    yv += __shfl_xor(yv, 4);
    yv += __shfl_xor(yv, 8);
    if (n == 0) {
      float zv  = zp[i * 768];
      float sil = zv / (1.f + __expf(-zv));
      yp[i * 384] = (yv + uv * Dv) * sil;
    }
  }
}

// ---------------- out_proj GEMM: out[b,o,l] = sum_d yy[row,d]*opw[o,d] ----------------
__global__ void k_outproj(const float* __restrict__ yy, const float* __restrict__ w,
                          float* __restrict__ out) {
  __shared__ float sA[64 * SA_P];
  __shared__ float sB[64 * SB_P];
  int t = threadIdx.x;
  int rowbase = blockIdx.x * 128;
  int nbase = blockIdx.y * 64;
  int tx = t & 15, ty = t >> 4;
  int n0 = tx * 4, m0 = ty * 8;
  float acc[8][4];
#pragma unroll
  for (int i = 0; i < 8; i++)
#pragma unroll
    for (int j = 0; j < 4; j++) acc[i][j] = 0.f;
  for (int c0 = 0; c0 < 384; c0 += 64) {
    if (c0) __syncthreads();
    stageA_rowmajor(yy, rowbase, 384, c0, sA, t);
    stageB(w, nbase, 384, c0, 192, sB, t);
    __syncthreads();
    gemm_inner(sA, sB, m0, n0, acc);
  }
  int b = rowbase / Lseq;
  int l0 = rowbase - b * Lseq + m0;
#pragma unroll
  for (int ni = 0; ni < 4; ni++) {
    int o = nbase + n0 + ni;
    long base = ((long)b * 192 + o) * Lseq + l0;
    *(float4*)(out + base) = make_float4(acc[0][ni], acc[1][ni], acc[2][ni], acc[3][ni]);
    *(float4*)(out + base + 4) = make_float4(acc[4][ni], acc[5][ni], acc[6][ni], acc[7][ni]);
  }
}

extern "C" void kernel_launch(void* const* d_in, const int* in_sizes, int n_in,
                              void* d_out, int out_size, void* d_ws, size_t ws_size,
                              hipStream_t stream) {
  const float* x    = (const float*)d_in[0];
  const float* guide= (const float*)d_in[1];
  const float* gw   = (const float*)d_in[2];
  const float* ln_g = (const float*)d_in[3];
  const float* ln_b = (const float*)d_in[4];
  const float* ipw  = (const float*)d_in[5];
  const float* cw   = (const float*)d_in[6];
  const float* cb   = (const float*)d_in[7];
  const float* xpw  = (const float*)d_in[8];
  const float* dtw  = (const float*)d_in[9];
  const float* dtb  = (const float*)d_in[10];
  const float* Alog = (const float*)d_in[11];
  const float* Dp   = (const float*)d_in[12];
  const float* opw  = (const float*)d_in[13];
  float* out = (float*)d_out;
  float* ws  = (float*)d_ws;

  float* gx  = ws + 0;          // 3145728
  float* seq = ws + 3145728;    // 3145728
  float* xz  = ws + 6291456;    // 12582912
  float* u   = ws + 18874368;   // 6291456
  float* dt  = ws + 25165824;   // 6291456
  float* Bc_ = ws + 31457280;   // 262144
  float* Cc_ = ws + 31719424;   // 262144
  float* Ap  = ws + 31981568;   // 786432
  float* Ss  = ws + 32768000;   // 786432
  float* Hs  = ws + 33554432;   // 786432
  float* dbc = ws + 0;          // reuse (gx/seq dead by k_xproj time)
  float* yy  = ws + 0;          // reuse (dbc dead by k_scan3 time)

  k_guide  <<<dim3(32, 3, 4),  256, 0, stream>>>(x, guide, gw, gx);
  k_ln     <<<dim3(128, 4),    256, 0, stream>>>(gx, ln_g, ln_b, seq);
  k_inproj <<<dim3(128, 12),   256, 0, stream>>>(seq, ipw, xz);
  k_conv   <<<24576,           256, 0, stream>>>(xz, cw, cb, u);
  k_xproj  <<<dim3(128, 1),    256, 0, stream>>>(u, xpw, dbc);
  k_dtsplit<<<24576,           256, 0, stream>>>(dbc, dtw, dtb, dt, Bc_, Cc_);
  k_scan1  <<<3072,            256, 0, stream>>>(dt, u, Bc_, Alog, Ap, Ss);
  k_scan2  <<<96,              256, 0, stream>>>(Ap, Ss, Hs);
  k_scan3  <<<3072,            256, 0, stream>>>(dt, u, Bc_, Cc_, Alog, Hs, Dp, xz, yy);
  k_outproj<<<dim3(128, 3),    256, 0, stream>>>(yy, opw, out);
}

// Round 4
// 404.624 us; speedup vs baseline: 3.0217x; 1.3645x over previous
//
#include <hip/hip_runtime.h>
#include <hip/hip_bf16.h>

#define Bsz 4
#define Cm 192
#define Lseq 4096
#define Din 384
#define Dst 16
#define NCk 128
#define CLk 32    // Lseq/NCk

// ======================= Tiled fp32 GEMM building blocks =======================
#define SA_P 132
#define SB_P 68

__device__ __forceinline__ void stageA_rowmajor(const float* __restrict__ A, int rowbase,
                                                int Kp, int c0, float* sA, int t) {
  int m = t >> 1;
  int cg = (t & 1) * 32;
  const float* src = A + (long)(rowbase + m) * Kp + c0 + cg;
#pragma unroll
  for (int j = 0; j < 8; j++) {
    float4 v = *(const float4*)(src + j * 4);
    int cc = cg + j * 4;
    sA[(cc + 0) * SA_P + m] = v.x;
    sA[(cc + 1) * SA_P + m] = v.y;
    sA[(cc + 2) * SA_P + m] = v.z;
    sA[(cc + 3) * SA_P + m] = v.w;
  }
}

__device__ __forceinline__ void stageA_colmajor(const float* __restrict__ A, long cbase,
                                                int Mp, int l0, float* sA, int t) {
  int cc = t >> 2;
  int mg = (t & 3) * 32;
  const float* src = A + (cbase + cc) * Mp + l0 + mg;
  float* dst = sA + cc * SA_P + mg;
#pragma unroll
  for (int j = 0; j < 8; j++) {
    *(float4*)(dst + j * 4) = *(const float4*)(src + j * 4);
  }
}

__device__ __forceinline__ void stageB(const float* __restrict__ B, int nbase, int Kp,
                                       int c0, int Nmax, float* sB, int t) {
  int n = t >> 2;
  int cg = (t & 3) * 16;
  bool ok = (nbase + n) < Nmax;
  const float* src = B + (long)(nbase + n) * Kp + c0 + cg;
#pragma unroll
  for (int j = 0; j < 4; j++) {
    float4 v = ok ? *(const float4*)(src + j * 4) : make_float4(0.f, 0.f, 0.f, 0.f);
    int cc = cg + j * 4;
    sB[(cc + 0) * SB_P + n] = v.x;
    sB[(cc + 1) * SB_P + n] = v.y;
    sB[(cc + 2) * SB_P + n] = v.z;
    sB[(cc + 3) * SB_P + n] = v.w;
  }
}

__device__ __forceinline__ void gemm_inner(const float* sA, const float* sB, int m0, int n0,
                                           float acc[8][4]) {
#pragma unroll
  for (int cc = 0; cc < 64; cc++) {
    float4 bv = *(const float4*)(sB + cc * SB_P + n0);
    float4 a0 = *(const float4*)(sA + cc * SA_P + m0);
    float4 a1 = *(const float4*)(sA + cc * SA_P + m0 + 4);
    float am[8] = {a0.x, a0.y, a0.z, a0.w, a1.x, a1.y, a1.z, a1.w};
    float bn[4] = {bv.x, bv.y, bv.z, bv.w};
#pragma unroll
    for (int mi = 0; mi < 8; mi++)
#pragma unroll
      for (int ni = 0; ni < 4; ni++)
        acc[mi][ni] = fmaf(am[mi], bn[ni], acc[mi][ni]);
  }
}

// ---------------- guide GEMM ----------------
__global__ void k_guide(const float* __restrict__ x, const float* __restrict__ guide,
                        const float* __restrict__ gw, float* __restrict__ gx) {
  __shared__ float sA[64 * SA_P];
  __shared__ float sB[64 * SB_P];
  int t = threadIdx.x;
  int l0 = blockIdx.x * 128;
  int nbase = blockIdx.y * 64;
  int b = blockIdx.z;
  int tx = t & 15, ty = t >> 4;
  int n0 = tx * 4, m0 = ty * 8;
  float acc[8][4];
#pragma unroll
  for (int i = 0; i < 8; i++)
#pragma unroll
    for (int j = 0; j < 4; j++) acc[i][j] = 0.f;
  for (int c0 = 0; c0 < 192; c0 += 64) {
    if (c0) __syncthreads();
    stageA_colmajor(guide, (long)b * 192 + c0, Lseq, l0, sA, t);
    stageB(gw, nbase, 192, c0, 192, sB, t);
    __syncthreads();
    gemm_inner(sA, sB, m0, n0, acc);
  }
#pragma unroll
  for (int ni = 0; ni < 4; ni++) {
    int o = nbase + n0 + ni;
    long base = ((long)b * 192 + o) * Lseq + l0 + m0;
    float4 x0 = *(const float4*)(x + base);
    float4 x1 = *(const float4*)(x + base + 4);
    float4 r0 = make_float4(acc[0][ni] + x0.x, acc[1][ni] + x0.y, acc[2][ni] + x0.z, acc[3][ni] + x0.w);
    float4 r1 = make_float4(acc[4][ni] + x1.x, acc[5][ni] + x1.y, acc[6][ni] + x1.z, acc[7][ni] + x1.w);
    *(float4*)(gx + base) = r0;
    *(float4*)(gx + base + 4) = r1;
  }
}

// ---------------- LayerNorm + transpose ----------------
__global__ void k_ln(const float* __restrict__ gx, const float* __restrict__ ln_g,
                     const float* __restrict__ ln_b, float* __restrict__ seq) {
  __shared__ float s[32][193];
  __shared__ float smu[32], srstd[32];
  int l0 = blockIdx.x * 32;
  int b  = blockIdx.y;
  int t  = threadIdx.x;
  for (int i = t; i < 192 * 32; i += 256) {
    int c = i >> 5, li = i & 31;
    s[li][c] = gx[(b * 192 + c) * Lseq + l0 + li];
  }
  __syncthreads();
  int li = t >> 3, j = t & 7;
  float sum = 0.f, sq = 0.f;
  for (int c = j; c < 192; c += 8) { float v = s[li][c]; sum += v; sq = fmaf(v, v, sq); }
  for (int off = 1; off < 8; off <<= 1) {
    sum += __shfl_xor(sum, off);
    sq  += __shfl_xor(sq, off);
  }
  if (j == 0) {
    float mu  = sum / 192.f;
    float var = sq / 192.f - mu * mu;
    smu[li]   = mu;
    srstd[li] = rsqrtf(var + 1e-5f);
  }
  __syncthreads();
  for (int i = t; i < 32 * 192; i += 256) {
    int li2 = i / 192, c = i % 192;
    float v = (s[li2][c] - smu[li2]) * srstd[li2] * ln_g[c] + ln_b[c];
    seq[(b * Lseq + l0 + li2) * 192 + c] = v;
  }
}

// ---------------- in_proj GEMM ----------------
__global__ void k_inproj(const float* __restrict__ seq, const float* __restrict__ w,
                         float* __restrict__ xz) {
  __shared__ float sA[64 * SA_P];
  __shared__ float sB[64 * SB_P];
  int t = threadIdx.x;
  int rowbase = blockIdx.x * 128;
  int nbase = blockIdx.y * 64;
  int tx = t & 15, ty = t >> 4;
  int n0 = tx * 4, m0 = ty * 8;
  float acc[8][4];
#pragma unroll
  for (int i = 0; i < 8; i++)
#pragma unroll
    for (int j = 0; j < 4; j++) acc[i][j] = 0.f;
  for (int c0 = 0; c0 < 192; c0 += 64) {
    if (c0) __syncthreads();
    stageA_rowmajor(seq, rowbase, 192, c0, sA, t);
    stageB(w, nbase, 192, c0, 768, sB, t);
    __syncthreads();
    gemm_inner(sA, sB, m0, n0, acc);
  }
#pragma unroll
  for (int mi = 0; mi < 8; mi++) {
    long row = rowbase + m0 + mi;
    *(float4*)(xz + row * 768 + nbase + n0) =
        make_float4(acc[mi][0], acc[mi][1], acc[mi][2], acc[mi][3]);
  }
}

// ---------------- causal depthwise conv4 + SiLU ----------------
__global__ void k_conv(const float* __restrict__ xz, const float* __restrict__ cw,
                       const float* __restrict__ cb, float* __restrict__ u) {
  int idx = blockIdx.x * 256 + threadIdx.x;
  if (idx >= Bsz * Lseq * Din) return;
  int d = idx % Din;
  int l = (idx / Din) % Lseq;
  int b = idx / (Din * Lseq);
  float acc = cb[d];
#pragma unroll
  for (int k = 0; k < 4; k++) {
    int ls = l - 3 + k;
    if (ls >= 0) acc = fmaf(xz[(b * Lseq + ls) * 768 + d], cw[d * 4 + k], acc);
  }
  u[idx] = acc / (1.f + __expf(-acc));
}

// ---------------- x_proj GEMM ----------------
__global__ void k_xproj(const float* __restrict__ u, const float* __restrict__ xw,
                        float* __restrict__ dbc) {
  __shared__ float sA[64 * SA_P];
  __shared__ float sB[64 * SB_P];
  int t = threadIdx.x;
  int rowbase = blockIdx.x * 128;
  int tx = t & 15, ty = t >> 4;
  int n0 = tx * 4, m0 = ty * 8;
  float acc[8][4];
#pragma unroll
  for (int i = 0; i < 8; i++)
#pragma unroll
    for (int j = 0; j < 4; j++) acc[i][j] = 0.f;
  for (int c0 = 0; c0 < 384; c0 += 64) {
    if (c0) __syncthreads();
    stageA_rowmajor(u, rowbase, 384, c0, sA, t);
    stageB(xw, 0, 384, c0, 44, sB, t);
    __syncthreads();
    gemm_inner(sA, sB, m0, n0, acc);
  }
  if (tx < 11) {
#pragma unroll
    for (int mi = 0; mi < 8; mi++) {
      long row = rowbase + m0 + mi;
      *(float4*)(dbc + row * 48 + n0) =
          make_float4(acc[mi][0], acc[mi][1], acc[mi][2], acc[mi][3]);
    }
  }
}

// ---------------- dt_proj + softplus + B/C split ----------------
__global__ void k_dtsplit(const float* __restrict__ dbc, const float* __restrict__ dtw,
                          const float* __restrict__ dtb, float* __restrict__ dt,
                          float* __restrict__ Bc, float* __restrict__ Cc) {
  int idx = blockIdx.x * 256 + threadIdx.x;
  int row = idx / 384;
  int d = idx % 384;
  const float* p = dbc + (long)row * 48;
  float acc = dtb[d];
#pragma unroll
  for (int r = 0; r < 12; r++) acc = fmaf(p[r], dtw[d * 12 + r], acc);
  float sp = (acc > 20.f) ? acc : __logf(1.f + __expf(acc));
  dt[(long)row * 384 + d] = sp;
  if (d < 16) Bc[row * 16 + d] = p[12 + d];
  else if (d < 32) Cc[row * 16 + (d - 16)] = p[28 + (d - 16)];
}

// ---------------- prep: A = -exp(A_log), rA = 1/A ----------------
__global__ void k_prep(const float* __restrict__ Alog, float* __restrict__ Aexp,
                       float* __restrict__ rAe) {
  int i = blockIdx.x * 256 + threadIdx.x;
  if (i < Din * Dst) {
    float A = -__expf(Alog[i]);
    Aexp[i] = A;
    rAe[i] = 1.f / A;
  }
}

// ---------------- scanA: per-chunk local scan, d-per-thread, h[16] in regs ----------------
__global__ void k_scanA(const float* __restrict__ dt, const float* __restrict__ u,
                        const float* __restrict__ Bc, const float* __restrict__ Aexp,
                        const float* __restrict__ rAe,
                        float* __restrict__ Ssum, float* __restrict__ Sdt) {
  int d = threadIdx.x;         // 0..383
  int c = blockIdx.x;          // chunk
  int b = blockIdx.y;
  float A[16], rA[16], h[16];
  const float4* Ap4 = (const float4*)(Aexp + d * 16);
  const float4* Rp4 = (const float4*)(rAe + d * 16);
#pragma unroll
  for (int j = 0; j < 4; j++) {
    float4 av = Ap4[j], rv = Rp4[j];
    A[4 * j + 0] = av.x; A[4 * j + 1] = av.y; A[4 * j + 2] = av.z; A[4 * j + 3] = av.w;
    rA[4 * j + 0] = rv.x; rA[4 * j + 1] = rv.y; rA[4 * j + 2] = rv.z; rA[4 * j + 3] = rv.w;
  }
#pragma unroll
  for (int n = 0; n < 16; n++) h[n] = 0.f;
  float sdt = 0.f;
  long row0 = (long)b * Lseq + (long)c * CLk;
  const float* dtp = dt + row0 * 384 + d;
  const float* up  = u  + row0 * 384 + d;
  const float* Bp  = Bc + row0 * 16;
#pragma unroll 2
  for (int i = 0; i < CLk; i++) {
    float dtv = dtp[i * 384];
    float uv  = up[i * 384];
    float Bv[16];
#pragma unroll
    for (int j = 0; j < 4; j++) {
      float4 bv = *(const float4*)(Bp + i * 16 + j * 4);
      Bv[4 * j + 0] = bv.x; Bv[4 * j + 1] = bv.y; Bv[4 * j + 2] = bv.z; Bv[4 * j + 3] = bv.w;
    }
    sdt += dtv;
#pragma unroll
    for (int n = 0; n < 16; n++) {
      float a = __expf(dtv * A[n]);
      float q = rA[n] * Bv[n] * uv;
      h[n] = fmaf(a, h[n] + q, -q);
    }
  }
  long o = ((long)(b * NCk + c) * 384 + d);
  Sdt[o] = sdt;
#pragma unroll
  for (int j = 0; j < 4; j++) {
    *(float4*)(Ssum + o * 16 + j * 4) = make_float4(h[4*j], h[4*j+1], h[4*j+2], h[4*j+3]);
  }
}

// ---------------- scanB: chunk combine over NCk chunks ----------------
__global__ void k_scanB(const float* __restrict__ Ssum, const float* __restrict__ Sdt,
                        const float* __restrict__ Aexp, float* __restrict__ Hst) {
  int g = blockIdx.x * 256 + threadIdx.x;   // 0..24575
  int n = g & 15;
  int d = (g >> 4) % 384;
  int b = g / (384 * 16);
  float A = Aexp[d * 16 + n];
  float h = 0.f;
  for (int c = 0; c < NCk; c++) {
    long o = ((long)(b * NCk + c) * 384 + d);
    float aC = __expf(A * Sdt[o]);
    Hst[o * 16 + n] = h;
    h = fmaf(aC, h, Ssum[o * 16 + n]);
  }
}

// ---------------- scanC: replay with init state, y = <h,C>, gate; write into xz u-half ----------------
__global__ void k_scanC(const float* __restrict__ dt, const float* __restrict__ u,
                        const float* __restrict__ Bc, const float* __restrict__ Cc,
                        const float* __restrict__ Aexp, const float* __restrict__ rAe,
                        const float* __restrict__ Hst, const float* __restrict__ Dp,
                        float* __restrict__ xz) {
  int d = threadIdx.x;
  int c = blockIdx.x;
  int b = blockIdx.y;
  float A[16], rA[16], h[16];
  const float4* Ap4 = (const float4*)(Aexp + d * 16);
  const float4* Rp4 = (const float4*)(rAe + d * 16);
#pragma unroll
  for (int j = 0; j < 4; j++) {
    float4 av = Ap4[j], rv = Rp4[j];
    A[4 * j + 0] = av.x; A[4 * j + 1] = av.y; A[4 * j + 2] = av.z; A[4 * j + 3] = av.w;
    rA[4 * j + 0] = rv.x; rA[4 * j + 1] = rv.y; rA[4 * j + 2] = rv.z; rA[4 * j + 3] = rv.w;
  }
  long o = ((long)(b * NCk + c) * 384 + d);
#pragma unroll
  for (int j = 0; j < 4; j++) {
    float4 hv = *(const float4*)(Hst + o * 16 + j * 4);
    h[4 * j + 0] = hv.x; h[4 * j + 1] = hv.y; h[4 * j + 2] = hv.z; h[4 * j + 3] = hv.w;
  }
  float Dv = Dp[d];
  long row0 = (long)b * Lseq + (long)c * CLk;
  const float* dtp = dt + row0 * 384 + d;
  const float* up  = u  + row0 * 384 + d;
  const float* Bp  = Bc + row0 * 16;
  const float* Cp  = Cc + row0 * 16;
  float* xzp = xz + row0 * 768;
#pragma unroll 2
  for (int i = 0; i < CLk; i++) {
    float dtv = dtp[i * 384];
    float uv  = up[i * 384];
    float zv  = xzp[i * 768 + 384 + d];
    float Bv[16], Cv[16];
#pragma unroll
    for (int j = 0; j < 4; j++) {
      float4 bv = *(const float4*)(Bp + i * 16 + j * 4);
      float4 cv = *(const float4*)(Cp + i * 16 + j * 4);
      Bv[4 * j + 0] = bv.x; Bv[4 * j + 1] = bv.y; Bv[4 * j + 2] = bv.z; Bv[4 * j + 3] = bv.w;
      Cv[4 * j + 0] = cv.x; Cv[4 * j + 1] = cv.y; Cv[4 * j + 2] = cv.z; Cv[4 * j + 3] = cv.w;
    }
    float yacc = 0.f;
#pragma unroll
    for (int n = 0; n < 16; n++) {
      float a = __expf(dtv * A[n]);
      float q = rA[n] * Bv[n] * uv;
      h[n] = fmaf(a, h[n] + q, -q);
      yacc = fmaf(h[n], Cv[n], yacc);
    }
    float sil = zv / (1.f + __expf(-zv));
    xzp[i * 768 + d] = (yacc + uv * Dv) * sil;
  }
}

// ---------------- out_proj GEMM: reads yy from xz u-half (pitch 768) ----------------
__global__ void k_outproj(const float* __restrict__ yy, const float* __restrict__ w,
                          float* __restrict__ out) {
  __shared__ float sA[64 * SA_P];
  __shared__ float sB[64 * SB_P];
  int t = threadIdx.x;
  int rowbase = blockIdx.x * 128;
  int nbase = blockIdx.y * 64;
  int tx = t & 15, ty = t >> 4;
  int n0 = tx * 4, m0 = ty * 8;
  float acc[8][4];
#pragma unroll
  for (int i = 0; i < 8; i++)
#pragma unroll
    for (int j = 0; j < 4; j++) acc[i][j] = 0.f;
  for (int c0 = 0; c0 < 384; c0 += 64) {
    if (c0) __syncthreads();
    stageA_rowmajor(yy, rowbase, 768, c0, sA, t);   // pitch 768: u-half holds y
    stageB(w, nbase, 384, c0, 192, sB, t);
    __syncthreads();
    gemm_inner(sA, sB, m0, n0, acc);
  }
  int b = rowbase / Lseq;
  int l0 = rowbase - b * Lseq + m0;
#pragma unroll
  for (int ni = 0; ni < 4; ni++) {
    int o = nbase + n0 + ni;
    long base = ((long)b * 192 + o) * Lseq + l0;
    *(float4*)(out + base) = make_float4(acc[0][ni], acc[1][ni], acc[2][ni], acc[3][ni]);
    *(float4*)(out + base + 4) = make_float4(acc[4][ni], acc[5][ni], acc[6][ni], acc[7][ni]);
  }
}

extern "C" void kernel_launch(void* const* d_in, const int* in_sizes, int n_in,
                              void* d_out, int out_size, void* d_ws, size_t ws_size,
                              hipStream_t stream) {
  const float* x    = (const float*)d_in[0];
  const float* guide= (const float*)d_in[1];
  const float* gw   = (const float*)d_in[2];
  const float* ln_g = (const float*)d_in[3];
  const float* ln_b = (const float*)d_in[4];
  const float* ipw  = (const float*)d_in[5];
  const float* cw   = (const float*)d_in[6];
  const float* cb   = (const float*)d_in[7];
  const float* xpw  = (const float*)d_in[8];
  const float* dtw  = (const float*)d_in[9];
  const float* dtb  = (const float*)d_in[10];
  const float* Alog = (const float*)d_in[11];
  const float* Dp   = (const float*)d_in[12];
  const float* opw  = (const float*)d_in[13];
  float* out = (float*)d_out;
  float* ws  = (float*)d_ws;

  // Workspace map (float offsets), lifetime-packed, max = 34340864 (proven bound):
  float* gx   = ws + 0;         // [guide->ln]     3145728
  float* seq  = ws + 3145728;   // [ln->inproj]    3145728
  float* xz   = ws + 6291456;   // [inproj->scanC/outproj] 12582912 (u-half reused as yy)
  float* u    = ws + 18874368;  // [conv->scans]   6291456
  float* dt   = ws + 25165824;  // [dtsplit->scans]6291456
  float* Bc_  = ws + 31457280;  // 262144
  float* Cc_  = ws + 31719424;  // 262144
  float* Sdt  = ws + 31981568;  // 196608
  float* Aexp = ws + 32178176;  // 6144
  float* rAe  = ws + 32184320;  // 6144
  float* dbc  = ws + 0;         // [xproj->dtsplit] 786432 (gx dead)
  float* Ssum = ws + 0;         // [scanA->scanB]  3145728 (dbc dead)
  float* Hst  = ws + 3145728;   // [scanB->scanC]  3145728 (seq dead)
  float* yy   = xz;             // scanC writes y into xz cols 0..384 (pitch 768)

  k_prep   <<<24,              256, 0, stream>>>(Alog, Aexp, rAe);
  k_guide  <<<dim3(32, 3, 4),  256, 0, stream>>>(x, guide, gw, gx);
  k_ln     <<<dim3(128, 4),    256, 0, stream>>>(gx, ln_g, ln_b, seq);
  k_inproj <<<dim3(128, 12),   256, 0, stream>>>(seq, ipw, xz);
  k_conv   <<<24576,           256, 0, stream>>>(xz, cw, cb, u);
  k_xproj  <<<dim3(128, 1),    256, 0, stream>>>(u, xpw, dbc);
  k_dtsplit<<<24576,           256, 0, stream>>>(dbc, dtw, dtb, dt, Bc_, Cc_);
  k_scanA  <<<dim3(NCk, Bsz),  384, 0, stream>>>(dt, u, Bc_, Aexp, rAe, Ssum, Sdt);
  k_scanB  <<<96,              256, 0, stream>>>(Ssum, Sdt, Aexp, Hst);
  k_scanC  <<<dim3(NCk, Bsz),  384, 0, stream>>>(dt, u, Bc_, Cc_, Aexp, rAe, Hst, Dp, yy);
  k_outproj<<<dim3(128, 3),    256, 0, stream>>>(yy, opw, out);
}

// Round 5
// 362.161 us; speedup vs baseline: 3.3760x; 1.1173x over previous
//
#include <hip/hip_runtime.h>
#include <hip/hip_bf16.h>

#define Bsz 4
#define Cm 192
#define Lseq 4096
#define Din 384
#define Dst 16
#define NCk 128
#define CLk 32    // Lseq/NCk

typedef short s8v __attribute__((ext_vector_type(8)));
typedef float f4v __attribute__((ext_vector_type(4)));
typedef unsigned short ushort_t;

// round-to-nearest-even fp32 -> bf16 (as ushort)
__device__ __forceinline__ unsigned int f2bf(float v) {
  unsigned int u = __float_as_uint(v);
  return (u + 0x7FFFu + ((u >> 16) & 1u)) >> 16;
}
__device__ __forceinline__ float bf2f(unsigned int h) {
  return __uint_as_float(h << 16);
}

// ======================= Tiled fp32 GEMM building blocks =======================
#define SA_P 132
#define SB_P 68

__device__ __forceinline__ void stageA_rowmajor(const float* __restrict__ A, int rowbase,
                                                int Kp, int c0, float* sA, int t) {
  int m = t >> 1;
  int cg = (t & 1) * 32;
  const float* src = A + (long)(rowbase + m) * Kp + c0 + cg;
#pragma unroll
  for (int j = 0; j < 8; j++) {
    float4 v = *(const float4*)(src + j * 4);
    int cc = cg + j * 4;
    sA[(cc + 0) * SA_P + m] = v.x;
    sA[(cc + 1) * SA_P + m] = v.y;
    sA[(cc + 2) * SA_P + m] = v.z;
    sA[(cc + 3) * SA_P + m] = v.w;
  }
}

__device__ __forceinline__ void stageA_colmajor(const float* __restrict__ A, long cbase,
                                                int Mp, int l0, float* sA, int t) {
  int cc = t >> 2;
  int mg = (t & 3) * 32;
  const float* src = A + (cbase + cc) * Mp + l0 + mg;
  float* dst = sA + cc * SA_P + mg;
#pragma unroll
  for (int j = 0; j < 8; j++) {
    *(float4*)(dst + j * 4) = *(const float4*)(src + j * 4);
  }
}

__device__ __forceinline__ void stageB(const float* __restrict__ B, int nbase, int Kp,
                                       int c0, int Nmax, float* sB, int t) {
  int n = t >> 2;
  int cg = (t & 3) * 16;
  bool ok = (nbase + n) < Nmax;
  const float* src = B + (long)(nbase + n) * Kp + c0 + cg;
#pragma unroll
  for (int j = 0; j < 4; j++) {
    float4 v = ok ? *(const float4*)(src + j * 4) : make_float4(0.f, 0.f, 0.f, 0.f);
    int cc = cg + j * 4;
    sB[(cc + 0) * SB_P + n] = v.x;
    sB[(cc + 1) * SB_P + n] = v.y;
    sB[(cc + 2) * SB_P + n] = v.z;
    sB[(cc + 3) * SB_P + n] = v.w;
  }
}

__device__ __forceinline__ void gemm_inner(const float* sA, const float* sB, int m0, int n0,
                                           float acc[8][4]) {
#pragma unroll
  for (int cc = 0; cc < 64; cc++) {
    float4 bv = *(const float4*)(sB + cc * SB_P + n0);
    float4 a0 = *(const float4*)(sA + cc * SA_P + m0);
    float4 a1 = *(const float4*)(sA + cc * SA_P + m0 + 4);
    float am[8] = {a0.x, a0.y, a0.z, a0.w, a1.x, a1.y, a1.z, a1.w};
    float bn[4] = {bv.x, bv.y, bv.z, bv.w};
#pragma unroll
    for (int mi = 0; mi < 8; mi++)
#pragma unroll
      for (int ni = 0; ni < 4; ni++)
        acc[mi][ni] = fmaf(am[mi], bn[ni], acc[mi][ni]);
  }
}

// ---------------- guide GEMM (fp32) ----------------
__global__ void k_guide(const float* __restrict__ x, const float* __restrict__ guide,
                        const float* __restrict__ gw, float* __restrict__ gx) {
  __shared__ float sA[64 * SA_P];
  __shared__ float sB[64 * SB_P];
  int t = threadIdx.x;
  int l0 = blockIdx.x * 128;
  int nbase = blockIdx.y * 64;
  int b = blockIdx.z;
  int tx = t & 15, ty = t >> 4;
  int n0 = tx * 4, m0 = ty * 8;
  float acc[8][4];
#pragma unroll
  for (int i = 0; i < 8; i++)
#pragma unroll
    for (int j = 0; j < 4; j++) acc[i][j] = 0.f;
  for (int c0 = 0; c0 < 192; c0 += 64) {
    if (c0) __syncthreads();
    stageA_colmajor(guide, (long)b * 192 + c0, Lseq, l0, sA, t);
    stageB(gw, nbase, 192, c0, 192, sB, t);
    __syncthreads();
    gemm_inner(sA, sB, m0, n0, acc);
  }
#pragma unroll
  for (int ni = 0; ni < 4; ni++) {
    int o = nbase + n0 + ni;
    long base = ((long)b * 192 + o) * Lseq + l0 + m0;
    float4 x0 = *(const float4*)(x + base);
    float4 x1 = *(const float4*)(x + base + 4);
    float4 r0 = make_float4(acc[0][ni] + x0.x, acc[1][ni] + x0.y, acc[2][ni] + x0.z, acc[3][ni] + x0.w);
    float4 r1 = make_float4(acc[4][ni] + x1.x, acc[5][ni] + x1.y, acc[6][ni] + x1.z, acc[7][ni] + x1.w);
    *(float4*)(gx + base) = r0;
    *(float4*)(gx + base + 4) = r1;
  }
}

// ---------------- LayerNorm + transpose, emit bf16 hi/lo ----------------
__global__ void k_ln(const float* __restrict__ gx, const float* __restrict__ ln_g,
                     const float* __restrict__ ln_b, ushort_t* __restrict__ seqh,
                     ushort_t* __restrict__ seql) {
  __shared__ float s[32][193];
  __shared__ float smu[32], srstd[32];
  int l0 = blockIdx.x * 32;
  int b  = blockIdx.y;
  int t  = threadIdx.x;
  for (int i = t; i < 192 * 32; i += 256) {
    int c = i >> 5, li = i & 31;
    s[li][c] = gx[(b * 192 + c) * Lseq + l0 + li];
  }
  __syncthreads();
  int li = t >> 3, j = t & 7;
  float sum = 0.f, sq = 0.f;
  for (int c = j; c < 192; c += 8) { float v = s[li][c]; sum += v; sq = fmaf(v, v, sq); }
  for (int off = 1; off < 8; off <<= 1) {
    sum += __shfl_xor(sum, off);
    sq  += __shfl_xor(sq, off);
  }
  if (j == 0) {
    float mu  = sum / 192.f;
    float var = sq / 192.f - mu * mu;
    smu[li]   = mu;
    srstd[li] = rsqrtf(var + 1e-5f);
  }
  __syncthreads();
  for (int i = t; i < 32 * 192; i += 256) {
    int li2 = i / 192, c = i % 192;
    float v = (s[li2][c] - smu[li2]) * srstd[li2] * ln_g[c] + ln_b[c];
    long idx = (long)(b * Lseq + l0 + li2) * 192 + c;
    unsigned int h = f2bf(v);
    seqh[idx] = (ushort_t)h;
    float lo = v - bf2f(h);
    seql[idx] = (ushort_t)f2bf(lo);
  }
}

// ---------------- weight split: fp32 -> bf16 hi/lo ----------------
__global__ void k_wsplit(const float* __restrict__ w, ushort_t* __restrict__ wh,
                         ushort_t* __restrict__ wl, int n) {
  int i = blockIdx.x * 256 + threadIdx.x;
  if (i < n) {
    float v = w[i];
    unsigned int h = f2bf(v);
    wh[i] = (ushort_t)h;
    wl[i] = (ushort_t)f2bf(v - bf2f(h));
  }
}

// ---------------- in_proj via split-bf16 MFMA ----------------
// xz[row][o] = sum_c seq[row][c] * ipw[o][c]  (C = A · B^T)
// A-frag lane layout: A[m=lane&15][k=quad*8+j]; B-frag: B[n=lane&15][k=quad*8+j]
// C/D: col = lane&15 (n), row = quad*4 + reg (m)   [m89-verified]
#define KP 72   // LDS pitch in bf16 elems (144 B, 16B-aligned rows)
__global__ __launch_bounds__(256) void k_inproj_mfma(
    const ushort_t* __restrict__ Ah, const ushort_t* __restrict__ Al,
    const ushort_t* __restrict__ Bh, const ushort_t* __restrict__ Bl,
    float* __restrict__ xz) {
  __shared__ ushort_t sAh[64 * KP], sAl[64 * KP], sBh[64 * KP], sBl[64 * KP];
  int t = threadIdx.x;
  int mbase = blockIdx.x * 64;
  int nbase = blockIdx.y * 64;
  int lane = t & 63, w = t >> 6;
  int wm = (w & 1) * 32, wn = (w >> 1) * 32;
  int q = lane >> 4, mr = lane & 15;
  f4v acc[2][2];
#pragma unroll
  for (int i = 0; i < 2; i++)
#pragma unroll
    for (int j = 0; j < 2; j++) acc[i][j] = (f4v){0.f, 0.f, 0.f, 0.f};

  for (int c0 = 0; c0 < 192; c0 += 64) {
    if (c0) __syncthreads();
    // stage 64 rows x 64 k of each of 4 matrices; 512 16B-segments each, 2 per thread
#pragma unroll
    for (int rep = 0; rep < 2; rep++) {
      int s = t + rep * 256;
      int row = s >> 3, kseg = (s & 7) * 8;
      long aoff = (long)(mbase + row) * 192 + c0 + kseg;
      long boff = (long)(nbase + row) * 192 + c0 + kseg;
      int doff = row * KP + kseg;
      *(uint4*)(sAh + doff) = *(const uint4*)(Ah + aoff);
      *(uint4*)(sAl + doff) = *(const uint4*)(Al + aoff);
      *(uint4*)(sBh + doff) = *(const uint4*)(Bh + boff);
      *(uint4*)(sBl + doff) = *(const uint4*)(Bl + boff);
    }
    __syncthreads();
#pragma unroll
    for (int k0 = 0; k0 < 64; k0 += 32) {
      s8v ah[2], al[2], bh[2], bl[2];
#pragma unroll
      for (int mt = 0; mt < 2; mt++) {
        int off = (wm + mt * 16 + mr) * KP + k0 + q * 8;
        ah[mt] = *(const s8v*)(sAh + off);
        al[mt] = *(const s8v*)(sAl + off);
      }
#pragma unroll
      for (int nt = 0; nt < 2; nt++) {
        int off = (wn + nt * 16 + mr) * KP + k0 + q * 8;
        bh[nt] = *(const s8v*)(sBh + off);
        bl[nt] = *(const s8v*)(sBl + off);
      }
#pragma unroll
      for (int mt = 0; mt < 2; mt++)
#pragma unroll
        for (int nt = 0; nt < 2; nt++) {
          acc[mt][nt] = __builtin_amdgcn_mfma_f32_16x16x32_bf16(ah[mt], bh[nt], acc[mt][nt], 0, 0, 0);
          acc[mt][nt] = __builtin_amdgcn_mfma_f32_16x16x32_bf16(ah[mt], bl[nt], acc[mt][nt], 0, 0, 0);
          acc[mt][nt] = __builtin_amdgcn_mfma_f32_16x16x32_bf16(al[mt], bh[nt], acc[mt][nt], 0, 0, 0);
        }
    }
  }
#pragma unroll
  for (int mt = 0; mt < 2; mt++)
#pragma unroll
    for (int nt = 0; nt < 2; nt++) {
      int row = mbase + wm + mt * 16 + q * 4;
      int col = nbase + wn + nt * 16 + mr;
#pragma unroll
      for (int r = 0; r < 4; r++)
        xz[(long)(row + r) * 768 + col] = acc[mt][nt][r];
    }
}

// ---------------- causal depthwise conv4 + SiLU ----------------
__global__ void k_conv(const float* __restrict__ xz, const float* __restrict__ cw,
                       const float* __restrict__ cb, float* __restrict__ u) {
  int idx = blockIdx.x * 256 + threadIdx.x;
  if (idx >= Bsz * Lseq * Din) return;
  int d = idx % Din;
  int l = (idx / Din) % Lseq;
  int b = idx / (Din * Lseq);
  float acc = cb[d];
#pragma unroll
  for (int k = 0; k < 4; k++) {
    int ls = l - 3 + k;
    if (ls >= 0) acc = fmaf(xz[(b * Lseq + ls) * 768 + d], cw[d * 4 + k], acc);
  }
  u[idx] = acc / (1.f + __expf(-acc));
}

// ---------------- x_proj GEMM (fp32) ----------------
__global__ void k_xproj(const float* __restrict__ u, const float* __restrict__ xw,
                        float* __restrict__ dbc) {
  __shared__ float sA[64 * SA_P];
  __shared__ float sB[64 * SB_P];
  int t = threadIdx.x;
  int rowbase = blockIdx.x * 128;
  int tx = t & 15, ty = t >> 4;
  int n0 = tx * 4, m0 = ty * 8;
  float acc[8][4];
#pragma unroll
  for (int i = 0; i < 8; i++)
#pragma unroll
    for (int j = 0; j < 4; j++) acc[i][j] = 0.f;
  for (int c0 = 0; c0 < 384; c0 += 64) {
    if (c0) __syncthreads();
    stageA_rowmajor(u, rowbase, 384, c0, sA, t);
    stageB(xw, 0, 384, c0, 44, sB, t);
    __syncthreads();
    gemm_inner(sA, sB, m0, n0, acc);
  }
  if (tx < 11) {
#pragma unroll
    for (int mi = 0; mi < 8; mi++) {
      long row = rowbase + m0 + mi;
      *(float4*)(dbc + row * 48 + n0) =
          make_float4(acc[mi][0], acc[mi][1], acc[mi][2], acc[mi][3]);
    }
  }
}

// ---------------- dt_proj + softplus + B/C split ----------------
__global__ void k_dtsplit(const float* __restrict__ dbc, const float* __restrict__ dtw,
                          const float* __restrict__ dtb, float* __restrict__ dt,
                          float* __restrict__ Bc, float* __restrict__ Cc) {
  int idx = blockIdx.x * 256 + threadIdx.x;
  int row = idx / 384;
  int d = idx % 384;
  const float* p = dbc + (long)row * 48;
  float acc = dtb[d];
#pragma unroll
  for (int r = 0; r < 12; r++) acc = fmaf(p[r], dtw[d * 12 + r], acc);
  float sp = (acc > 20.f) ? acc : __logf(1.f + __expf(acc));
  dt[(long)row * 384 + d] = sp;
  if (d < 16) Bc[row * 16 + d] = p[12 + d];
  else if (d < 32) Cc[row * 16 + (d - 16)] = p[28 + (d - 16)];
}

// ---------------- prep: A = -exp(A_log), rA = 1/A ----------------
__global__ void k_prep(const float* __restrict__ Alog, float* __restrict__ Aexp,
                       float* __restrict__ rAe) {
  int i = blockIdx.x * 256 + threadIdx.x;
  if (i < Din * Dst) {
    float A = -__expf(Alog[i]);
    Aexp[i] = A;
    rAe[i] = 1.f / A;
  }
}

// ---------------- scanA ----------------
__global__ void k_scanA(const float* __restrict__ dt, const float* __restrict__ u,
                        const float* __restrict__ Bc, const float* __restrict__ Aexp,
                        const float* __restrict__ rAe,
                        float* __restrict__ Ssum, float* __restrict__ Sdt) {
  int d = threadIdx.x;
  int c = blockIdx.x;
  int b = blockIdx.y;
  float A[16], rA[16], h[16];
  const float4* Ap4 = (const float4*)(Aexp + d * 16);
  const float4* Rp4 = (const float4*)(rAe + d * 16);
#pragma unroll
  for (int j = 0; j < 4; j++) {
    float4 av = Ap4[j], rv = Rp4[j];
    A[4 * j + 0] = av.x; A[4 * j + 1] = av.y; A[4 * j + 2] = av.z; A[4 * j + 3] = av.w;
    rA[4 * j + 0] = rv.x; rA[4 * j + 1] = rv.y; rA[4 * j + 2] = rv.z; rA[4 * j + 3] = rv.w;
  }
#pragma unroll
  for (int n = 0; n < 16; n++) h[n] = 0.f;
  float sdt = 0.f;
  long row0 = (long)b * Lseq + (long)c * CLk;
  const float* dtp = dt + row0 * 384 + d;
  const float* up  = u  + row0 * 384 + d;
  const float* Bp  = Bc + row0 * 16;
#pragma unroll 2
  for (int i = 0; i < CLk; i++) {
    float dtv = dtp[i * 384];
    float uv  = up[i * 384];
    float Bv[16];
#pragma unroll
    for (int j = 0; j < 4; j++) {
      float4 bv = *(const float4*)(Bp + i * 16 + j * 4);
      Bv[4 * j + 0] = bv.x; Bv[4 * j + 1] = bv.y; Bv[4 * j + 2] = bv.z; Bv[4 * j + 3] = bv.w;
    }
    sdt += dtv;
#pragma unroll
    for (int n = 0; n < 16; n++) {
      float a = __expf(dtv * A[n]);
      float q = rA[n] * Bv[n] * uv;
      h[n] = fmaf(a, h[n] + q, -q);
    }
  }
  long o = ((long)(b * NCk + c) * 384 + d);
  Sdt[o] = sdt;
#pragma unroll
  for (int j = 0; j < 4; j++) {
    *(float4*)(Ssum + o * 16 + j * 4) = make_float4(h[4*j], h[4*j+1], h[4*j+2], h[4*j+3]);
  }
}

// ---------------- scanB ----------------
__global__ void k_scanB(const float* __restrict__ Ssum, const float* __restrict__ Sdt,
                        const float* __restrict__ Aexp, float* __restrict__ Hst) {
  int g = blockIdx.x * 256 + threadIdx.x;
  int n = g & 15;
  int d = (g >> 4) % 384;
  int b = g / (384 * 16);
  float A = Aexp[d * 16 + n];
  float h = 0.f;
  for (int c = 0; c < NCk; c++) {
    long o = ((long)(b * NCk + c) * 384 + d);
    float aC = __expf(A * Sdt[o]);
    Hst[o * 16 + n] = h;
    h = fmaf(aC, h, Ssum[o * 16 + n]);
  }
}

// ---------------- scanC ----------------
__global__ void k_scanC(const float* __restrict__ dt, const float* __restrict__ u,
                        const float* __restrict__ Bc, const float* __restrict__ Cc,
                        const float* __restrict__ Aexp, const float* __restrict__ rAe,
                        const float* __restrict__ Hst, const float* __restrict__ Dp,
                        float* __restrict__ xz) {
  int d = threadIdx.x;
  int c = blockIdx.x;
  int b = blockIdx.y;
  float A[16], rA[16], h[16];
  const float4* Ap4 = (const float4*)(Aexp + d * 16);
  const float4* Rp4 = (const float4*)(rAe + d * 16);
#pragma unroll
  for (int j = 0; j < 4; j++) {
    float4 av = Ap4[j], rv = Rp4[j];
    A[4 * j + 0] = av.x; A[4 * j + 1] = av.y; A[4 * j + 2] = av.z; A[4 * j + 3] = av.w;
    rA[4 * j + 0] = rv.x; rA[4 * j + 1] = rv.y; rA[4 * j + 2] = rv.z; rA[4 * j + 3] = rv.w;
  }
  long o = ((long)(b * NCk + c) * 384 + d);
#pragma unroll
  for (int j = 0; j < 4; j++) {
    float4 hv = *(const float4*)(Hst + o * 16 + j * 4);
    h[4 * j + 0] = hv.x; h[4 * j + 1] = hv.y; h[4 * j + 2] = hv.z; h[4 * j + 3] = hv.w;
  }
  float Dv = Dp[d];
  long row0 = (long)b * Lseq + (long)c * CLk;
  const float* dtp = dt + row0 * 384 + d;
  const float* up  = u  + row0 * 384 + d;
  const float* Bp  = Bc + row0 * 16;
  const float* Cp  = Cc + row0 * 16;
  float* xzp = xz + row0 * 768;
#pragma unroll 2
  for (int i = 0; i < CLk; i++) {
    float dtv = dtp[i * 384];
    float uv  = up[i * 384];
    float zv  = xzp[i * 768 + 384 + d];
    float Bv[16], Cv[16];
#pragma unroll
    for (int j = 0; j < 4; j++) {
      float4 bv = *(const float4*)(Bp + i * 16 + j * 4);
      float4 cv = *(const float4*)(Cp + i * 16 + j * 4);
      Bv[4 * j + 0] = bv.x; Bv[4 * j + 1] = bv.y; Bv[4 * j + 2] = bv.z; Bv[4 * j + 3] = bv.w;
      Cv[4 * j + 0] = cv.x; Cv[4 * j + 1] = cv.y; Cv[4 * j + 2] = cv.z; Cv[4 * j + 3] = cv.w;
    }
    float yacc = 0.f;
#pragma unroll
    for (int n = 0; n < 16; n++) {
      float a = __expf(dtv * A[n]);
      float q = rA[n] * Bv[n] * uv;
      h[n] = fmaf(a, h[n] + q, -q);
      yacc = fmaf(h[n], Cv[n], yacc);
    }
    float sil = zv / (1.f + __expf(-zv));
    xzp[i * 768 + d] = (yacc + uv * Dv) * sil;
  }
}

// ---------------- out_proj GEMM (fp32, reads yy from xz u-half, pitch 768) ----------------
__global__ void k_outproj(const float* __restrict__ yy, const float* __restrict__ w,
                          float* __restrict__ out) {
  __shared__ float sA[64 * SA_P];
  __shared__ float sB[64 * SB_P];
  int t = threadIdx.x;
  int rowbase = blockIdx.x * 128;
  int nbase = blockIdx.y * 64;
  int tx = t & 15, ty = t >> 4;
  int n0 = tx * 4, m0 = ty * 8;
  float acc[8][4];
#pragma unroll
  for (int i = 0; i < 8; i++)
#pragma unroll
    for (int j = 0; j < 4; j++) acc[i][j] = 0.f;
  for (int c0 = 0; c0 < 384; c0 += 64) {
    if (c0) __syncthreads();
    stageA_rowmajor(yy, rowbase, 768, c0, sA, t);
    stageB(w, nbase, 384, c0, 192, sB, t);
    __syncthreads();
    gemm_inner(sA, sB, m0, n0, acc);
  }
  int b = rowbase / Lseq;
  int l0 = rowbase - b * Lseq + m0;
#pragma unroll
  for (int ni = 0; ni < 4; ni++) {
    int o = nbase + n0 + ni;
    long base = ((long)b * 192 + o) * Lseq + l0;
    *(float4*)(out + base) = make_float4(acc[0][ni], acc[1][ni], acc[2][ni], acc[3][ni]);
    *(float4*)(out + base + 4) = make_float4(acc[4][ni], acc[5][ni], acc[6][ni], acc[7][ni]);
  }
}

extern "C" void kernel_launch(void* const* d_in, const int* in_sizes, int n_in,
                              void* d_out, int out_size, void* d_ws, size_t ws_size,
                              hipStream_t stream) {
  const float* x    = (const float*)d_in[0];
  const float* guide= (const float*)d_in[1];
  const float* gw   = (const float*)d_in[2];
  const float* ln_g = (const float*)d_in[3];
  const float* ln_b = (const float*)d_in[4];
  const float* ipw  = (const float*)d_in[5];
  const float* cw   = (const float*)d_in[6];
  const float* cb   = (const float*)d_in[7];
  const float* xpw  = (const float*)d_in[8];
  const float* dtw  = (const float*)d_in[9];
  const float* dtb  = (const float*)d_in[10];
  const float* Alog = (const float*)d_in[11];
  const float* Dp   = (const float*)d_in[12];
  const float* opw  = (const float*)d_in[13];
  float* out = (float*)d_out;
  float* ws  = (float*)d_ws;

  // Workspace (float offsets), lifetime-packed, max 32337920 floats (< proven 34340864):
  float* gx   = ws + 0;         // [guide->ln]   3145728
  ushort_t* seqh = (ushort_t*)(ws + 3145728);            // 3145728 bf16 = 1572864 f
  ushort_t* seql = (ushort_t*)(ws + 3145728 + 1572864);  // 1572864 f
  float* xz   = ws + 6291456;   // 12582912 (u-half reused as yy)
  float* u    = ws + 18874368;  // 6291456
  float* dt   = ws + 25165824;  // 6291456
  float* Bc_  = ws + 31457280;  // 262144
  float* Cc_  = ws + 31719424;  // 262144
  float* Sdt  = ws + 31981568;  // 196608
  float* Aexp = ws + 32178176;  // 6144
  float* rAe  = ws + 32184320;  // 6144
  ushort_t* wh = (ushort_t*)(ws + 32190464);  // 147456 bf16 = 73728 f
  ushort_t* wl = (ushort_t*)(ws + 32264192);  // 73728 f -> end 32337920
  float* dbc  = ws + 0;         // [xproj->dtsplit] (gx dead)
  float* Ssum = ws + 0;         // [scanA->scanB] (dbc dead)
  float* Hst  = ws + 3145728;   // [scanB->scanC] (seqh/seql dead)
  float* yy   = xz;             // scanC writes y into xz cols 0..384

  k_prep   <<<24,              256, 0, stream>>>(Alog, Aexp, rAe);
  k_wsplit <<<576,             256, 0, stream>>>(ipw, wh, wl, 768 * 192);
  k_guide  <<<dim3(32, 3, 4),  256, 0, stream>>>(x, guide, gw, gx);
  k_ln     <<<dim3(128, 4),    256, 0, stream>>>(gx, ln_g, ln_b, seqh, seql);
  k_inproj_mfma<<<dim3(256, 12), 256, 0, stream>>>(seqh, seql, wh, wl, xz);
  k_conv   <<<24576,           256, 0, stream>>>(xz, cw, cb, u);
  k_xproj  <<<dim3(128, 1),    256, 0, stream>>>(u, xpw, dbc);
  k_dtsplit<<<24576,           256, 0, stream>>>(dbc, dtw, dtb, dt, Bc_, Cc_);
  k_scanA  <<<dim3(NCk, Bsz),  384, 0, stream>>>(dt, u, Bc_, Aexp, rAe, Ssum, Sdt);
  k_scanB  <<<96,              256, 0, stream>>>(Ssum, Sdt, Aexp, Hst);
  k_scanC  <<<dim3(NCk, Bsz),  384, 0, stream>>>(dt, u, Bc_, Cc_, Aexp, rAe, Hst, Dp, yy);
  k_outproj<<<dim3(128, 3),    256, 0, stream>>>(yy, opw, out);
}

// Round 6
// 309.740 us; speedup vs baseline: 3.9473x; 1.1692x over previous
//
#include <hip/hip_runtime.h>
#include <hip/hip_bf16.h>

#define Bsz 4
#define Cm 192
#define Lseq 4096
#define Din 384
#define Dst 16
#define NCk 128
#define CLk 32    // Lseq/NCk

typedef short s8v __attribute__((ext_vector_type(8)));
typedef float f4v __attribute__((ext_vector_type(4)));
typedef unsigned short ushort_t;

__device__ __forceinline__ unsigned int f2bf(float v) {
  unsigned int u = __float_as_uint(v);
  return (u + 0x7FFFu + ((u >> 16) & 1u)) >> 16;
}
__device__ __forceinline__ float bf2f(unsigned int h) {
  return __uint_as_float(h << 16);
}

// ======================= split-bf16 MFMA GEMM core =======================
// 64x64 block tile, 4 waves (2x2 of 32x32), K-chunks of 64.
// A[m][k], B[n][k] both k-contiguous bf16 hi/lo. C = A*B^T in fp32 via
// 3-MFMA split (ah*bh + ah*bl + al*bh). Layouts m89-verified.
#define KP 72

template<int K, int NMAX>
__device__ __forceinline__ void mfma_gemm64(
    const ushort_t* __restrict__ Ah, const ushort_t* __restrict__ Al, long arow0,
    const ushort_t* __restrict__ Bh, const ushort_t* __restrict__ Bl, int nbase,
    ushort_t* sAh, ushort_t* sAl, ushort_t* sBh, ushort_t* sBl,
    f4v acc[2][2]) {
  int t = threadIdx.x;
  int lane = t & 63, w = t >> 6;
  int wm = (w & 1) * 32, wn = (w >> 1) * 32;
  int q = lane >> 4, mr = lane & 15;
  for (int c0 = 0; c0 < K; c0 += 64) {
    if (c0) __syncthreads();
#pragma unroll
    for (int rep = 0; rep < 2; rep++) {
      int s = t + rep * 256;
      int row = s >> 3, kseg = (s & 7) * 8;
      long aoff = (arow0 + row) * (long)K + c0 + kseg;
      int doff = row * KP + kseg;
      *(uint4*)(sAh + doff) = *(const uint4*)(Ah + aoff);
      *(uint4*)(sAl + doff) = *(const uint4*)(Al + aoff);
      if (NMAX >= 64 || (nbase + row) < NMAX) {
        long boff = (long)(nbase + row) * K + c0 + kseg;
        *(uint4*)(sBh + doff) = *(const uint4*)(Bh + boff);
        *(uint4*)(sBl + doff) = *(const uint4*)(Bl + boff);
      } else {
        uint4 z = make_uint4(0u, 0u, 0u, 0u);
        *(uint4*)(sBh + doff) = z;
        *(uint4*)(sBl + doff) = z;
      }
    }
    __syncthreads();
#pragma unroll
    for (int k0 = 0; k0 < 64; k0 += 32) {
      s8v ah[2], al[2], bh[2], bl[2];
#pragma unroll
      for (int mt = 0; mt < 2; mt++) {
        int off = (wm + mt * 16 + mr) * KP + k0 + q * 8;
        ah[mt] = *(const s8v*)(sAh + off);
        al[mt] = *(const s8v*)(sAl + off);
      }
#pragma unroll
      for (int nt = 0; nt < 2; nt++) {
        int off = (wn + nt * 16 + mr) * KP + k0 + q * 8;
        bh[nt] = *(const s8v*)(sBh + off);
        bl[nt] = *(const s8v*)(sBl + off);
      }
#pragma unroll
      for (int mt = 0; mt < 2; mt++)
#pragma unroll
        for (int nt = 0; nt < 2; nt++) {
          acc[mt][nt] = __builtin_amdgcn_mfma_f32_16x16x32_bf16(ah[mt], bh[nt], acc[mt][nt], 0, 0, 0);
          acc[mt][nt] = __builtin_amdgcn_mfma_f32_16x16x32_bf16(ah[mt], bl[nt], acc[mt][nt], 0, 0, 0);
          acc[mt][nt] = __builtin_amdgcn_mfma_f32_16x16x32_bf16(al[mt], bh[nt], acc[mt][nt], 0, 0, 0);
        }
    }
  }
}

// ---------------- weight split: all 4 weights, fp32 -> bf16 hi/lo ----------------
// layout in wsplit arena (ushorts): gwh@0(36864) gwl@36864 iwh@73728(147456)
// iwl@221184 xwh@368640(16896) xwl@385536 opwh@402432(73728) opwl@476160 end 549888
__global__ void k_wsplit4(const float* __restrict__ gw, const float* __restrict__ ipw,
                          const float* __restrict__ xw, const float* __restrict__ opw,
                          ushort_t* __restrict__ base) {
  int i = blockIdx.x * 256 + threadIdx.x;
  const float* src; ushort_t *dh, *dl; int off;
  if (i < 36864)        { src = gw;  off = i;           dh = base;          dl = base + 36864; }
  else if (i < 184320)  { src = ipw; off = i - 36864;   dh = base + 73728;  dl = base + 221184; }
  else if (i < 201216)  { src = xw;  off = i - 184320;  dh = base + 368640; dl = base + 385536; }
  else if (i < 274944)  { src = opw; off = i - 201216;  dh = base + 402432; dl = base + 476160; }
  else return;
  float v = src[off];
  unsigned int h = f2bf(v);
  dh[off] = (ushort_t)h;
  dl[off] = (ushort_t)f2bf(v - bf2f(h));
}

// ---------------- pre: transpose x,guide (b,c,l)->(b,l,c); guide also split ----------------
__global__ void k_pre(const float* __restrict__ x, const float* __restrict__ guide,
                      float* __restrict__ xT, ushort_t* __restrict__ gTh,
                      ushort_t* __restrict__ gTl) {
  __shared__ float sx[64 * 68];
  __shared__ float sg[64 * 68];
  int t = threadIdx.x;
  int l0 = blockIdx.x * 64;
  int c0 = blockIdx.y * 64;
  int b  = blockIdx.z;
#pragma unroll
  for (int ii = 0; ii < 4; ii++) {
    int ci = (t >> 4) + ii * 16;
    int j4 = (t & 15) * 4;
    long src = ((long)(b * 192 + c0 + ci)) * Lseq + l0 + j4;
    *(float4*)(sx + ci * 68 + j4) = *(const float4*)(x + src);
    *(float4*)(sg + ci * 68 + j4) = *(const float4*)(guide + src);
  }
  __syncthreads();
#pragma unroll
  for (int ii = 0; ii < 4; ii++) {
    int li = (t >> 4) + ii * 16;
    int c4 = (t & 15) * 4;
    long dst = ((long)(b * Lseq + l0 + li)) * 192 + c0 + c4;
    float4 xv = make_float4(sx[(c4 + 0) * 68 + li], sx[(c4 + 1) * 68 + li],
                            sx[(c4 + 2) * 68 + li], sx[(c4 + 3) * 68 + li]);
    *(float4*)(xT + dst) = xv;
    float gv[4];
#pragma unroll
    for (int j = 0; j < 4; j++) gv[j] = sg[(c4 + j) * 68 + li];
    ushort4 hv, lv;
    unsigned int h0 = f2bf(gv[0]), h1 = f2bf(gv[1]), h2 = f2bf(gv[2]), h3 = f2bf(gv[3]);
    hv.x = h0; hv.y = h1; hv.z = h2; hv.w = h3;
    lv.x = (ushort_t)f2bf(gv[0] - bf2f(h0));
    lv.y = (ushort_t)f2bf(gv[1] - bf2f(h1));
    lv.z = (ushort_t)f2bf(gv[2] - bf2f(h2));
    lv.w = (ushort_t)f2bf(gv[3] - bf2f(h3));
    *(ushort4*)(gTh + dst) = hv;
    *(ushort4*)(gTl + dst) = lv;
  }
}

// ---------------- guide GEMM (MFMA): gxT[row,o] = xT[row,o] + sum_c gT[row,c]*gw[o,c] ----------------
__global__ __launch_bounds__(256) void k_guide_mfma(
    const ushort_t* __restrict__ Ah, const ushort_t* __restrict__ Al,
    const ushort_t* __restrict__ Bh, const ushort_t* __restrict__ Bl,
    const float* __restrict__ xT, float* __restrict__ gxT) {
  __shared__ __align__(16) ushort_t smem[4 * 64 * KP];
  ushort_t* sAh = smem;
  ushort_t* sAl = smem + 64 * KP;
  ushort_t* sBh = smem + 2 * 64 * KP;
  ushort_t* sBl = smem + 3 * 64 * KP;
  int t = threadIdx.x;
  int rowbase = blockIdx.x * 64;
  int nbase = blockIdx.y * 64;
  int lane = t & 63, w = t >> 6;
  int wm = (w & 1) * 32, wn = (w >> 1) * 32;
  int q = lane >> 4, mr = lane & 15;
  f4v acc[2][2];
#pragma unroll
  for (int i = 0; i < 2; i++)
#pragma unroll
    for (int j = 0; j < 2; j++) acc[i][j] = (f4v){0.f, 0.f, 0.f, 0.f};
  mfma_gemm64<192, 192>(Ah, Al, rowbase, Bh, Bl, nbase, sAh, sAl, sBh, sBl, acc);
#pragma unroll
  for (int mt = 0; mt < 2; mt++)
#pragma unroll
    for (int nt = 0; nt < 2; nt++) {
      int row = rowbase + wm + mt * 16 + q * 4;
      int col = nbase + wn + nt * 16 + mr;
#pragma unroll
      for (int r = 0; r < 4; r++) {
        long idx = (long)(row + r) * 192 + col;
        gxT[idx] = acc[mt][nt][r] + xT[idx];
      }
    }
}

// ---------------- row-major LayerNorm: gxT(b,l,c) -> seq bf16 hi/lo ----------------
__global__ void k_lnT(const float* __restrict__ gxT, const float* __restrict__ ln_g,
                      const float* __restrict__ ln_b, ushort_t* __restrict__ seqh,
                      ushort_t* __restrict__ seql) {
  int t = threadIdx.x;
  int r = blockIdx.x * 4 + (t >> 6);
  int lane = t & 63;
  const float* p = gxT + (long)r * 192;
  float v0 = p[lane], v1 = p[lane + 64], v2 = p[lane + 128];
  float sum = v0 + v1 + v2;
  float sq = fmaf(v0, v0, fmaf(v1, v1, v2 * v2));
#pragma unroll
  for (int off = 1; off < 64; off <<= 1) {
    sum += __shfl_xor(sum, off);
    sq  += __shfl_xor(sq, off);
  }
  float mu = sum / 192.f;
  float rstd = rsqrtf(sq / 192.f - mu * mu + 1e-5f);
  long base = (long)r * 192;
#pragma unroll
  for (int j = 0; j < 3; j++) {
    int c = lane + j * 64;
    float v = (p[c] - mu) * rstd * ln_g[c] + ln_b[c];
    unsigned int h = f2bf(v);
    seqh[base + c] = (ushort_t)h;
    seql[base + c] = (ushort_t)f2bf(v - bf2f(h));
  }
}

// ---------------- in_proj (MFMA): -> xzu (cols 0..383), z (cols 384..767), both pitch 384 ----------------
__global__ __launch_bounds__(256) void k_inproj_mfma(
    const ushort_t* __restrict__ Ah, const ushort_t* __restrict__ Al,
    const ushort_t* __restrict__ Bh, const ushort_t* __restrict__ Bl,
    float* __restrict__ xzu, float* __restrict__ z) {
  __shared__ __align__(16) ushort_t smem[4 * 64 * KP];
  ushort_t* sAh = smem;
  ushort_t* sAl = smem + 64 * KP;
  ushort_t* sBh = smem + 2 * 64 * KP;
  ushort_t* sBl = smem + 3 * 64 * KP;
  int t = threadIdx.x;
  int rowbase = blockIdx.x * 64;
  int nbase = blockIdx.y * 64;
  int lane = t & 63, w = t >> 6;
  int wm = (w & 1) * 32, wn = (w >> 1) * 32;
  int q = lane >> 4, mr = lane & 15;
  f4v acc[2][2];
#pragma unroll
  for (int i = 0; i < 2; i++)
#pragma unroll
    for (int j = 0; j < 2; j++) acc[i][j] = (f4v){0.f, 0.f, 0.f, 0.f};
  mfma_gemm64<192, 768>(Ah, Al, rowbase, Bh, Bl, nbase, sAh, sAl, sBh, sBl, acc);
  float* dst = (nbase < 384) ? xzu : z;
  int cb = (nbase < 384) ? nbase : nbase - 384;
#pragma unroll
  for (int mt = 0; mt < 2; mt++)
#pragma unroll
    for (int nt = 0; nt < 2; nt++) {
      int row = rowbase + wm + mt * 16 + q * 4;
      int col = cb + wn + nt * 16 + mr;
#pragma unroll
      for (int r = 0; r < 4; r++)
        dst[(long)(row + r) * 384 + col] = acc[mt][nt][r];
    }
}

// ---------------- causal depthwise conv4 + SiLU; emit u fp32 + bf16 hi/lo ----------------
__global__ void k_conv(const float* __restrict__ xzu, const float* __restrict__ cw,
                       const float* __restrict__ cb, float* __restrict__ u,
                       ushort_t* __restrict__ uh, ushort_t* __restrict__ ul) {
  int idx = blockIdx.x * 256 + threadIdx.x;
  if (idx >= Bsz * Lseq * Din) return;
  int d = idx % Din;
  int l = (idx / Din) % Lseq;
  float acc = cb[d];
#pragma unroll
  for (int k = 0; k < 4; k++) {
    int ls = l - 3 + k;
    if (ls >= 0) acc = fmaf(xzu[idx - (3 - k) * 384], cw[d * 4 + k], acc);
  }
  float v = acc / (1.f + __expf(-acc));
  u[idx] = v;
  unsigned int h = f2bf(v);
  uh[idx] = (ushort_t)h;
  ul[idx] = (ushort_t)f2bf(v - bf2f(h));
}

// ---------------- x_proj (MFMA): dbc[row, r<44] pitch 48 ----------------
__global__ __launch_bounds__(256) void k_xproj_mfma(
    const ushort_t* __restrict__ Ah, const ushort_t* __restrict__ Al,
    const ushort_t* __restrict__ Bh, const ushort_t* __restrict__ Bl,
    float* __restrict__ dbc) {
  __shared__ __align__(16) ushort_t smem[4 * 64 * KP];
  ushort_t* sAh = smem;
  ushort_t* sAl = smem + 64 * KP;
  ushort_t* sBh = smem + 2 * 64 * KP;
  ushort_t* sBl = smem + 3 * 64 * KP;
  int t = threadIdx.x;
  int rowbase = blockIdx.x * 64;
  int lane = t & 63, w = t >> 6;
  int wm = (w & 1) * 32, wn = (w >> 1) * 32;
  int q = lane >> 4, mr = lane & 15;
  f4v acc[2][2];
#pragma unroll
  for (int i = 0; i < 2; i++)
#pragma unroll
    for (int j = 0; j < 2; j++) acc[i][j] = (f4v){0.f, 0.f, 0.f, 0.f};
  mfma_gemm64<384, 44>(Ah, Al, rowbase, Bh, Bl, 0, sAh, sAl, sBh, sBl, acc);
#pragma unroll
  for (int mt = 0; mt < 2; mt++)
#pragma unroll
    for (int nt = 0; nt < 2; nt++) {
      int row = rowbase + wm + mt * 16 + q * 4;
      int col = wn + nt * 16 + mr;
      if (col < 44) {
#pragma unroll
        for (int r = 0; r < 4; r++)
          dbc[(long)(row + r) * 48 + col] = acc[mt][nt][r];
      }
    }
}

// ---------------- dt_proj + softplus + B/C split ----------------
__global__ void k_dtsplit(const float* __restrict__ dbc, const float* __restrict__ dtw,
                          const float* __restrict__ dtb, float* __restrict__ dt,
                          float* __restrict__ Bc, float* __restrict__ Cc) {
  int idx = blockIdx.x * 256 + threadIdx.x;
  int row = idx / 384;
  int d = idx % 384;
  const float* p = dbc + (long)row * 48;
  float acc = dtb[d];
#pragma unroll
  for (int r = 0; r < 12; r++) acc = fmaf(p[r], dtw[d * 12 + r], acc);
  float sp = (acc > 20.f) ? acc : __logf(1.f + __expf(acc));
  dt[(long)row * 384 + d] = sp;
  if (d < 16) Bc[row * 16 + d] = p[12 + d];
  else if (d < 32) Cc[row * 16 + (d - 16)] = p[28 + (d - 16)];
}

// ---------------- prep: A = -exp(A_log), rA = 1/A ----------------
__global__ void k_prep(const float* __restrict__ Alog, float* __restrict__ Aexp,
                       float* __restrict__ rAe) {
  int i = blockIdx.x * 256 + threadIdx.x;
  if (i < Din * Dst) {
    float A = -__expf(Alog[i]);
    Aexp[i] = A;
    rAe[i] = 1.f / A;
  }
}

// ---------------- scanA ----------------
__global__ void k_scanA(const float* __restrict__ dt, const float* __restrict__ u,
                        const float* __restrict__ Bc, const float* __restrict__ Aexp,
                        const float* __restrict__ rAe,
                        float* __restrict__ Ssum, float* __restrict__ Sdt) {
  int d = threadIdx.x;
  int c = blockIdx.x;
  int b = blockIdx.y;
  float A[16], rA[16], h[16];
  const float4* Ap4 = (const float4*)(Aexp + d * 16);
  const float4* Rp4 = (const float4*)(rAe + d * 16);
#pragma unroll
  for (int j = 0; j < 4; j++) {
    float4 av = Ap4[j], rv = Rp4[j];
    A[4 * j + 0] = av.x; A[4 * j + 1] = av.y; A[4 * j + 2] = av.z; A[4 * j + 3] = av.w;
    rA[4 * j + 0] = rv.x; rA[4 * j + 1] = rv.y; rA[4 * j + 2] = rv.z; rA[4 * j + 3] = rv.w;
  }
#pragma unroll
  for (int n = 0; n < 16; n++) h[n] = 0.f;
  float sdt = 0.f;
  long row0 = (long)b * Lseq + (long)c * CLk;
  const float* dtp = dt + row0 * 384 + d;
  const float* up  = u  + row0 * 384 + d;
  const float* Bp  = Bc + row0 * 16;
#pragma unroll 2
  for (int i = 0; i < CLk; i++) {
    float dtv = dtp[i * 384];
    float uv  = up[i * 384];
    float Bv[16];
#pragma unroll
    for (int j = 0; j < 4; j++) {
      float4 bv = *(const float4*)(Bp + i * 16 + j * 4);
      Bv[4 * j + 0] = bv.x; Bv[4 * j + 1] = bv.y; Bv[4 * j + 2] = bv.z; Bv[4 * j + 3] = bv.w;
    }
    sdt += dtv;
#pragma unroll
    for (int n = 0; n < 16; n++) {
      float a = __expf(dtv * A[n]);
      float q = rA[n] * Bv[n] * uv;
      h[n] = fmaf(a, h[n] + q, -q);
    }
  }
  long o = ((long)(b * NCk + c) * 384 + d);
  Sdt[o] = sdt;
#pragma unroll
  for (int j = 0; j < 4; j++) {
    *(float4*)(Ssum + o * 16 + j * 4) = make_float4(h[4*j], h[4*j+1], h[4*j+2], h[4*j+3]);
  }
}

// ---------------- scanB ----------------
__global__ void k_scanB(const float* __restrict__ Ssum, const float* __restrict__ Sdt,
                        const float* __restrict__ Aexp, float* __restrict__ Hst) {
  int g = blockIdx.x * 256 + threadIdx.x;
  int n = g & 15;
  int d = (g >> 4) % 384;
  int b = g / (384 * 16);
  float A = Aexp[d * 16 + n];
  float h = 0.f;
  for (int c = 0; c < NCk; c++) {
    long o = ((long)(b * NCk + c) * 384 + d);
    float aC = __expf(A * Sdt[o]);
    Hst[o * 16 + n] = h;
    h = fmaf(aC, h, Ssum[o * 16 + n]);
  }
}

// ---------------- scanC: replay, y=<h,C>, gate; emit y as bf16 hi/lo ----------------
__global__ void k_scanC(const float* __restrict__ dt, const float* __restrict__ u,
                        const float* __restrict__ Bc, const float* __restrict__ Cc,
                        const float* __restrict__ Aexp, const float* __restrict__ rAe,
                        const float* __restrict__ Hst, const float* __restrict__ Dp,
                        const float* __restrict__ z, ushort_t* __restrict__ yyh,
                        ushort_t* __restrict__ yyl) {
  int d = threadIdx.x;
  int c = blockIdx.x;
  int b = blockIdx.y;
  float A[16], rA[16], h[16];
  const float4* Ap4 = (const float4*)(Aexp + d * 16);
  const float4* Rp4 = (const float4*)(rAe + d * 16);
#pragma unroll
  for (int j = 0; j < 4; j++) {
    float4 av = Ap4[j], rv = Rp4[j];
    A[4 * j + 0] = av.x; A[4 * j + 1] = av.y; A[4 * j + 2] = av.z; A[4 * j + 3] = av.w;
    rA[4 * j + 0] = rv.x; rA[4 * j + 1] = rv.y; rA[4 * j + 2] = rv.z; rA[4 * j + 3] = rv.w;
  }
  long o = ((long)(b * NCk + c) * 384 + d);
#pragma unroll
  for (int j = 0; j < 4; j++) {
    float4 hv = *(const float4*)(Hst + o * 16 + j * 4);
    h[4 * j + 0] = hv.x; h[4 * j + 1] = hv.y; h[4 * j + 2] = hv.z; h[4 * j + 3] = hv.w;
  }
  float Dv = Dp[d];
  long row0 = (long)b * Lseq + (long)c * CLk;
  const float* dtp = dt + row0 * 384 + d;
  const float* up  = u  + row0 * 384 + d;
  const float* Bp  = Bc + row0 * 16;
  const float* Cp  = Cc + row0 * 16;
  const float* zp  = z + row0 * 384 + d;
#pragma unroll 2
  for (int i = 0; i < CLk; i++) {
    float dtv = dtp[i * 384];
    float uv  = up[i * 384];
    float zv  = zp[i * 384];
    float Bv[16], Cv[16];
#pragma unroll
    for (int j = 0; j < 4; j++) {
      float4 bv = *(const float4*)(Bp + i * 16 + j * 4);
      float4 cv = *(const float4*)(Cp + i * 16 + j * 4);
      Bv[4 * j + 0] = bv.x; Bv[4 * j + 1] = bv.y; Bv[4 * j + 2] = bv.z; Bv[4 * j + 3] = bv.w;
      Cv[4 * j + 0] = cv.x; Cv[4 * j + 1] = cv.y; Cv[4 * j + 2] = cv.z; Cv[4 * j + 3] = cv.w;
    }
    float yacc = 0.f;
#pragma unroll
    for (int n = 0; n < 16; n++) {
      float a = __expf(dtv * A[n]);
      float q = rA[n] * Bv[n] * uv;
      h[n] = fmaf(a, h[n] + q, -q);
      yacc = fmaf(h[n], Cv[n], yacc);
    }
    float sil = zv / (1.f + __expf(-zv));
    float yv = (yacc + uv * Dv) * sil;
    unsigned int hb = f2bf(yv);
    yyh[row0 * 384 + i * 384 + d] = (ushort_t)hb;
    yyl[row0 * 384 + i * 384 + d] = (ushort_t)f2bf(yv - bf2f(hb));
  }
}

// ---------------- out_proj (MFMA) with LDS transpose epilogue -> out (b,o,l) ----------------
__global__ __launch_bounds__(256) void k_outproj_mfma(
    const ushort_t* __restrict__ Ah, const ushort_t* __restrict__ Al,
    const ushort_t* __restrict__ Bh, const ushort_t* __restrict__ Bl,
    float* __restrict__ out) {
  __shared__ __align__(16) ushort_t smem[4 * 64 * KP];
  ushort_t* sAh = smem;
  ushort_t* sAl = smem + 64 * KP;
  ushort_t* sBh = smem + 2 * 64 * KP;
  ushort_t* sBl = smem + 3 * 64 * KP;
  float* sC = (float*)smem;   // 64*68 floats = 17408 B < 4*9216 B
  int t = threadIdx.x;
  int rowbase = blockIdx.x * 64;
  int nbase = blockIdx.y * 64;
  int lane = t & 63, w = t >> 6;
  int wm = (w & 1) * 32, wn = (w >> 1) * 32;
  int q = lane >> 4, mr = lane & 15;
  f4v acc[2][2];
#pragma unroll
  for (int i = 0; i < 2; i++)
#pragma unroll
    for (int j = 0; j < 2; j++) acc[i][j] = (f4v){0.f, 0.f, 0.f, 0.f};
  mfma_gemm64<384, 192>(Ah, Al, rowbase, Bh, Bl, nbase, sAh, sAl, sBh, sBl, acc);
  __syncthreads();
#pragma unroll
  for (int mt = 0; mt < 2; mt++)
#pragma unroll
    for (int nt = 0; nt < 2; nt++) {
      int rloc = wm + mt * 16 + q * 4;
      int cloc = wn + nt * 16 + mr;
#pragma unroll
      for (int r = 0; r < 4; r++)
        sC[(rloc + r) * 68 + cloc] = acc[mt][nt][r];
    }
  __syncthreads();
  // store transposed: out[(b*192 + nbase+o)*L + l0 + lg..lg+15]
  int b = rowbase >> 12;           // /4096
  int l0 = rowbase & 4095;
  int o = t >> 2;
  int lg = (t & 3) * 16;
  long obase = ((long)(b * 192 + nbase + o)) * Lseq + l0 + lg;
#pragma unroll
  for (int j4 = 0; j4 < 4; j4++) {
    float4 v = make_float4(sC[(lg + j4 * 4 + 0) * 68 + o], sC[(lg + j4 * 4 + 1) * 68 + o],
                           sC[(lg + j4 * 4 + 2) * 68 + o], sC[(lg + j4 * 4 + 3) * 68 + o]);
    *(float4*)(out + obase + j4 * 4) = v;
  }
}

extern "C" void kernel_launch(void* const* d_in, const int* in_sizes, int n_in,
                              void* d_out, int out_size, void* d_ws, size_t ws_size,
                              hipStream_t stream) {
  const float* x    = (const float*)d_in[0];
  const float* guide= (const float*)d_in[1];
  const float* gw   = (const float*)d_in[2];
  const float* ln_g = (const float*)d_in[3];
  const float* ln_b = (const float*)d_in[4];
  const float* ipw  = (const float*)d_in[5];
  const float* cw   = (const float*)d_in[6];
  const float* cb   = (const float*)d_in[7];
  const float* xpw  = (const float*)d_in[8];
  const float* dtw  = (const float*)d_in[9];
  const float* dtb  = (const float*)d_in[10];
  const float* Alog = (const float*)d_in[11];
  const float* Dp   = (const float*)d_in[12];
  const float* opw  = (const float*)d_in[13];
  float* out = (float*)d_out;
  float* ws  = (float*)d_ws;

  // Workspace (float offsets), lifetime-packed, max 32465408 < proven 34340864:
  // R0 [0,3145728):       xT [pre->guide] | uh(us) [conv->xproj] | Ssum [scanA->scanB]
  // R1 [3145728,6291456): gTh+gTl(us) [pre->guide] | ul(us) [conv->xproj] | Hst [scanB->scanC]
  // R2 [6291456,9437184): gxT [guide->lnT] | dbc [xproj->dtsplit] | yyh(us) [scanC->outproj]
  // R3 [9437184,12582912): seqh+seql(us) [lnT->inproj] | yyl(us) [scanC->outproj]
  // R4 [12582912,18874368): z [inproj->scanC]
  // R5 [18874368,25165824): xzu [inproj->conv] | dt [dtsplit->scanC]
  // R6 [25165824,31457280): u [conv->scanC]
  float* xT   = ws + 0;
  ushort_t* uh   = (ushort_t*)(ws + 0);
  float* Ssum = ws + 0;
  ushort_t* gTh  = (ushort_t*)(ws + 3145728);
  ushort_t* gTl  = (ushort_t*)(ws + 3145728 + 1572864);
  ushort_t* ul   = (ushort_t*)(ws + 3145728);
  float* Hst  = ws + 3145728;
  float* gxT  = ws + 6291456;
  float* dbc  = ws + 6291456;
  ushort_t* yyh  = (ushort_t*)(ws + 6291456);
  ushort_t* seqh = (ushort_t*)(ws + 9437184);
  ushort_t* seql = (ushort_t*)(ws + 9437184 + 1572864);
  ushort_t* yyl  = (ushort_t*)(ws + 9437184);
  float* z    = ws + 12582912;
  float* xzu  = ws + 18874368;
  float* dt   = ws + 18874368;
  float* u    = ws + 25165824;
  float* Bc_  = ws + 31457280;
  float* Cc_  = ws + 31719424;
  float* Sdt  = ws + 31981568;
  float* Aexp = ws + 32178176;
  float* rAe  = ws + 32184320;
  ushort_t* wsplit = (ushort_t*)(ws + 32190464);   // 549888 ushorts
  ushort_t* gwh = wsplit;
  ushort_t* gwl = wsplit + 36864;
  ushort_t* iwh = wsplit + 73728;
  ushort_t* iwl = wsplit + 221184;
  ushort_t* xwh = wsplit + 368640;
  ushort_t* xwl = wsplit + 385536;
  ushort_t* opwh = wsplit + 402432;
  ushort_t* opwl = wsplit + 476160;

  k_prep    <<<24,               256, 0, stream>>>(Alog, Aexp, rAe);
  k_wsplit4 <<<1074,             256, 0, stream>>>(gw, ipw, xpw, opw, wsplit);
  k_pre     <<<dim3(64, 3, 4),   256, 0, stream>>>(x, guide, xT, gTh, gTl);
  k_guide_mfma<<<dim3(256, 3),   256, 0, stream>>>(gTh, gTl, gwh, gwl, xT, gxT);
  k_lnT     <<<4096,             256, 0, stream>>>(gxT, ln_g, ln_b, seqh, seql);
  k_inproj_mfma<<<dim3(256, 12), 256, 0, stream>>>(seqh, seql, iwh, iwl, xzu, z);
  k_conv    <<<24576,            256, 0, stream>>>(xzu, cw, cb, u, uh, ul);
  k_xproj_mfma<<<256,            256, 0, stream>>>(uh, ul, xwh, xwl, dbc);
  k_dtsplit <<<24576,            256, 0, stream>>>(dbc, dtw, dtb, dt, Bc_, Cc_);
  k_scanA   <<<dim3(NCk, Bsz),   384, 0, stream>>>(dt, u, Bc_, Aexp, rAe, Ssum, Sdt);
  k_scanB   <<<96,               256, 0, stream>>>(Ssum, Sdt, Aexp, Hst);
  k_scanC   <<<dim3(NCk, Bsz),   384, 0, stream>>>(dt, u, Bc_, Cc_, Aexp, rAe, Hst, Dp, z, yyh, yyl);
  k_outproj_mfma<<<dim3(256, 3), 256, 0, stream>>>(yyh, yyl, opwh, opwl, out);
}